// Round 8
// baseline (515.388 us; speedup 1.0000x reference)
//
#include <hip/hip_runtime.h>
#include <stdint.h>

// LateralInhibition: out = inputs * ((inputs @ w1 + b) > 0), w1 = w with zero diag.
// v8 = v7 (scaled f16 split-precision MFMA + fixup) with the fixup made
//      BIT-IDENTICAL to the proven fp32 path.
//  - v6/v7 both failed with identical absmax 0.1836: a boundary element whose
//    true |inhib| ~ 1e-6 (below fp32 ordering noise). It WAS flagged (v7 error
//    bound 1e-6 << EPS=1e-3), so the fixup itself produced the wrong sign: its
//    lane-split + butterfly reduction is a different fp32 association than the
//    reference. v1/v3/v4/v5 (strict k-sequential fmaf) all scored absmax 0.0.
//  - fix: fixup = one thread per flagged element, s = fmaf(a[k], w[k], s) for
//    k ascending, + bias. Identical op sequence to v4's accumulator ->
//    bit-identical result -> matches reference everywhere v4 did (everywhere).
// Numerics (unchanged from v7): A*2^12, W*2^13 pre-scale (kills f16 denormal
// flush), hi/lo split with lo*2^11; 3 MFMA products; epilogue /2^25 exact;
// |inh| <= 1e-3 flagged (error bound ~1e-6, 1000x margin).
// Structure (unchanged): 128x128 tile, 4 waves 2x2, mfma_f32_16x16x32_f16,
// global_load_lds double-buffer (v4-proven, conflicts=0), XOR swizzle
// s(row)=(row>>1)&3 on both DMA source and LDS read, XCD-chunked block
// swizzle, v4 fp32 fallback if ws too small.

#define NUMD 512
#define EPS 1e-3f
#define FIXCAP (1u << 20)
#define SA 4096.0f                   // 2^12
#define SW 8192.0f                   // 2^13
#define INV_S (1.0f / 33554432.0f)   // 2^-25
#define INV_LO (1.0f / 2048.0f)      // 2^-11

typedef _Float16 f16;
typedef _Float16 f16x8 __attribute__((ext_vector_type(8)));
typedef _Float16 f16x4 __attribute__((ext_vector_type(4)));
typedef float    f32x4 __attribute__((ext_vector_type(4)));

#define GLOAD_LDS16(g, l)                                                      \
  __builtin_amdgcn_global_load_lds(                                            \
      (const __attribute__((address_space(1))) void*)(g),                      \
      (__attribute__((address_space(3))) void*)(l), 16, 0, 0)

// ---------------- pre-pass: W transpose + diag-zero + scaled f16 split ----------------
__global__ __launch_bounds__(256) void wprep(
    const float* __restrict__ W, float* __restrict__ Wt,
    f16* __restrict__ WtH, f16* __restrict__ WtL, unsigned* __restrict__ cnt)
{
    const int n = blockIdx.x;
    if (n == 0 && threadIdx.x == 0) *cnt = 0;
    for (int k = threadIdx.x; k < NUMD; k += 256) {
        float v = W[(size_t)k * NUMD + n];
        if (k == n) v = 0.0f;
        Wt[(size_t)n * NUMD + k] = v;          // unscaled fp32 for fixup
        const float vs = v * SW;
        f16 h = (f16)vs;
        WtH[(size_t)n * NUMD + k] = h;
        WtL[(size_t)n * NUMD + k] = (f16)((vs - (float)h) * 2048.0f);
    }
}

// ---------------- pre-pass: A scaled f16 split (lo additionally x 2^11) ----------------
__global__ __launch_bounds__(256) void aprep(
    const float* __restrict__ A, f16* __restrict__ AH, f16* __restrict__ AL,
    long total4)
{
    for (long i = (long)blockIdx.x * blockDim.x + threadIdx.x; i < total4;
         i += (long)gridDim.x * blockDim.x) {
        float4 a = ((const float4*)A)[i];
        const float* ap = (const float*)&a;
        f16x4 h, lo;
#pragma unroll
        for (int e = 0; e < 4; ++e) {
            const float as = ap[e] * SA;
            f16 hv = (f16)as;
            h[e]  = hv;
            lo[e] = (f16)((as - (float)hv) * 2048.0f);
        }
        ((f16x4*)AH)[i] = h;
        ((f16x4*)AL)[i] = lo;
    }
}

// ---------------- main GEMM (scaled f16 split MFMA) ----------------
__global__ __launch_bounds__(256, 1) void li_mfma(
    const float* __restrict__ A,    // [M,512] fp32 (epilogue gate input)
    const f16* __restrict__ AH, const f16* __restrict__ AL,
    const f16* __restrict__ WtH, const f16* __restrict__ WtL, // [n][k]
    const float* __restrict__ bias,
    float* __restrict__ out,
    unsigned* __restrict__ cnt, unsigned* __restrict__ list,
    int M, int cpx)
{
    // planes: 0=A_hi 1=A_lo 2=B_hi 3=B_lo ; [2 bufs][4 planes][128 rows][32 k] f16
    __shared__ __align__(16) f16 lds[2][4][128][32];   // 64 KiB

    const int tid = threadIdx.x;
    const int l   = tid & 63;
    const int wv  = tid >> 6;     // wave 0..3
    const int wr  = wv >> 1;      // wave row 0..1
    const int wc  = wv & 1;       // wave col 0..1
    const int lG  = l >> 4;       // k-chunk group 0..3
    const int lM  = l & 15;       // frag row/col

    int w = blockIdx.x;
    if (cpx) { const int xcd = w & 7, c = w >> 3; w = xcd * cpx + c; }
    const int m0  = (w >> 2) * 128;
    const int n0b = (w & 3) * 128;

    // DMA staging: dest = wave-uniform base + lane*16; lane l covers
    // row rq=(wv*32+(l>>2)), chunk gq=l&3; source pre-swizzled g = gq ^ s(row),
    // s(row) = (row>>1)&3; read side applies the same XOR.
    const int rq  = wv * 32 + (l >> 2);
    const int gq  = l & 3;
    const int s0  = (rq >> 1) & 3;
    const int s1  = ((rq + 16) >> 1) & 3;
    const size_t aOff0 = ((size_t)(m0 + rq)       * NUMD + (size_t)((gq ^ s0) * 8)) * 2;
    const size_t aOff1 = ((size_t)(m0 + rq + 16)  * NUMD + (size_t)((gq ^ s1) * 8)) * 2;
    const size_t bOff0 = ((size_t)(n0b + rq)      * NUMD + (size_t)((gq ^ s0) * 8)) * 2;
    const size_t bOff1 = ((size_t)(n0b + rq + 16) * NUMD + (size_t)((gq ^ s1) * 8)) * 2;
    const char* pAH = (const char*)AH;
    const char* pAL = (const char*)AL;
    const char* pBH = (const char*)WtH;
    const char* pBL = (const char*)WtL;

#define STAGE(nb, ktb) do {                                                    \
    GLOAD_LDS16(pAH + aOff0 + (ktb), &lds[nb][0][wv * 32][0]);                 \
    GLOAD_LDS16(pAH + aOff1 + (ktb), &lds[nb][0][wv * 32 + 16][0]);            \
    GLOAD_LDS16(pAL + aOff0 + (ktb), &lds[nb][1][wv * 32][0]);                 \
    GLOAD_LDS16(pAL + aOff1 + (ktb), &lds[nb][1][wv * 32 + 16][0]);            \
    GLOAD_LDS16(pBH + bOff0 + (ktb), &lds[nb][2][wv * 32][0]);                 \
    GLOAD_LDS16(pBH + bOff1 + (ktb), &lds[nb][2][wv * 32 + 16][0]);            \
    GLOAD_LDS16(pBL + bOff0 + (ktb), &lds[nb][3][wv * 32][0]);                 \
    GLOAD_LDS16(pBL + bOff1 + (ktb), &lds[nb][3][wv * 32 + 16][0]);            \
  } while (0)

    int aRd[4], bRd[4];
#pragma unroll
    for (int f = 0; f < 4; ++f) {
        const int mr = wr * 64 + f * 16 + lM;
        aRd[f] = mr * 64 + ((lG ^ ((mr >> 1) & 3)) << 4);
        const int nr = wc * 64 + f * 16 + lM;
        bRd[f] = nr * 64 + ((lG ^ ((nr >> 1) & 3)) << 4);
    }

    f32x4 accH[4][4], accL[4][4];
#pragma unroll
    for (int i = 0; i < 4; ++i)
#pragma unroll
        for (int j = 0; j < 4; ++j) {
            accH[i][j] = f32x4{0.f, 0.f, 0.f, 0.f};
            accL[i][j] = f32x4{0.f, 0.f, 0.f, 0.f};
        }

    STAGE(0, 0);

    const int NT = NUMD / 32;   // 16
    for (int kt = 0; kt < NT; ++kt) {
        const int cur = kt & 1;
        __syncthreads();                       // drains tile-kt DMAs (vmcnt0+barrier)
        if (kt + 1 < NT) STAGE(cur ^ 1, (size_t)(kt + 1) * 64);

        const char* PAH = (const char*)&lds[cur][0][0][0];
        const char* PAL = (const char*)&lds[cur][1][0][0];
        const char* PBH = (const char*)&lds[cur][2][0][0];
        const char* PBL = (const char*)&lds[cur][3][0][0];

        f16x8 bh[4], bl[4];
#pragma unroll
        for (int fj = 0; fj < 4; ++fj) {
            bh[fj] = *(const f16x8*)(PBH + bRd[fj]);
            bl[fj] = *(const f16x8*)(PBL + bRd[fj]);
        }
#pragma unroll
        for (int fi = 0; fi < 4; ++fi) {
            const f16x8 ah = *(const f16x8*)(PAH + aRd[fi]);
            const f16x8 al = *(const f16x8*)(PAL + aRd[fi]);
#pragma unroll
            for (int fj = 0; fj < 4; ++fj) {
                accH[fi][fj] = __builtin_amdgcn_mfma_f32_16x16x32_f16(ah, bh[fj], accH[fi][fj], 0, 0, 0);
                accL[fi][fj] = __builtin_amdgcn_mfma_f32_16x16x32_f16(ah, bl[fj], accL[fi][fj], 0, 0, 0);
                accL[fi][fj] = __builtin_amdgcn_mfma_f32_16x16x32_f16(al, bh[fj], accL[fi][fj], 0, 0, 0);
            }
        }
    }

    // epilogue: C/D layout col=lane&15, row=(lane>>4)*4+reg (m89-verified)
#pragma unroll
    for (int fj = 0; fj < 4; ++fj) {
        const int n = n0b + wc * 64 + fj * 16 + lM;
        const float bvj = bias[n];
#pragma unroll
        for (int fi = 0; fi < 4; ++fi) {
            const int mb = m0 + wr * 64 + fi * 16 + lG * 4;
#pragma unroll
            for (int r = 0; r < 4; ++r) {
                const size_t idx = (size_t)(mb + r) * NUMD + n;
                const float inh =
                    (accH[fi][fj][r] + accL[fi][fj][r] * INV_LO) * INV_S + bvj;
                const float x = A[idx];
                out[idx] = (inh > 0.0f) ? x : 0.0f;
                if (__builtin_fabsf(inh) <= EPS) {
                    unsigned p = atomicAdd(cnt, 1u);
                    if (p < FIXCAP) list[p] = (unsigned)idx;
                }
            }
        }
    }
#undef STAGE
}

// ------- fixup: exact fp32 recompute, BIT-IDENTICAL order to the proven v4 path -------
// One thread per flagged element; s = fmaf(a[k], w[k], s) for k = 0..511
// ascending, then + bias. Same fp32 op sequence as v4's accumulator (which
// scored absmax 0.0 on this dataset) -> same sign at every element.
__global__ __launch_bounds__(256) void fixup(
    const float* __restrict__ A, const float* __restrict__ Wt, // Wt[n][k] diag-zeroed
    const float* __restrict__ bias, float* __restrict__ out,
    const unsigned* __restrict__ cnt, const unsigned* __restrict__ list,
    unsigned total)
{
    unsigned nfix = *cnt;
    if (nfix > FIXCAP) nfix = FIXCAP;
    for (unsigned e = blockIdx.x * blockDim.x + threadIdx.x; e < nfix;
         e += gridDim.x * blockDim.x) {
        const unsigned code = list[e];
        if (code >= total) continue;           // safety guard
        const int n = (int)(code & 511);
        const float* ar = A  + (size_t)(code >> 9) * NUMD;
        const float* wr = Wt + (size_t)n * NUMD;
        float s = 0.0f;
#pragma unroll 8
        for (int k = 0; k < NUMD; ++k)
            s = fmaf(ar[k], wr[k], s);         // strict k-ascending chain
        const float inh = s + bias[n];
        out[code] = (inh > 0.0f) ? A[code] : 0.0f;
    }
}

// ---------------- fallback: v4 exact fp32 path (proven 205us) ----------------
#define BM 128
#define BN 256
#define BK 16
#define TM 8
#define TN 16
#define NTF (NUMD / BK)

__global__ __launch_bounds__(256) void zero_diag_kernel(
    const float* __restrict__ W, float* __restrict__ Wz)
{
    const int f = (int)(blockIdx.x * blockDim.x + threadIdx.x) * 4;
    const int row = f >> 9, col0 = f & 511;
    float4 v = *(const float4*)(W + f);
    if (row == col0 + 0) v.x = 0.0f;
    if (row == col0 + 1) v.y = 0.0f;
    if (row == col0 + 2) v.z = 0.0f;
    if (row == col0 + 3) v.w = 0.0f;
    *(float4*)(Wz + f) = v;
}

template<bool ZDIAG>
__global__ __launch_bounds__(256, 1) void li_gemm_fp32(
    const float* __restrict__ A, const float* __restrict__ Wm,
    const float* __restrict__ bias, float* __restrict__ out, int M)
{
    __shared__ __align__(16) float As[2][BM][BK];
    __shared__ __align__(16) float Bs[2][BK][BN];
    const int tid = threadIdx.x, lane = tid & 63, wv = tid >> 6;
    const int tc = tid & 15, tr = tid >> 4;
    const int m0 = blockIdx.x * BM, n0 = blockIdx.y * BN;
    const int am0 = wv * 32 + (lane >> 2), am1 = am0 + 16;
    const int q0 = ((lane & 3) ^ ((am0 >> 3) & 3)) << 2;
    const int q1 = ((lane & 3) ^ ((am1 >> 3) & 3)) << 2;
    const float* aSrc0 = A + (size_t)(m0 + am0) * NUMD + q0;
    const float* aSrc1 = A + (size_t)(m0 + am1) * NUMD + q1;
    const float* wSrc = Wm + (size_t)(wv * 4) * NUMD + n0 + lane * 4;
    float acc[TM][TN];
#pragma unroll
    for (int i = 0; i < TM; ++i)
#pragma unroll
        for (int j = 0; j < TN; ++j) acc[i][j] = 0.0f;
    GLOAD_LDS16(aSrc0, &As[0][wv * 32][0]);
    GLOAD_LDS16(aSrc1, &As[0][wv * 32 + 16][0]);
#pragma unroll
    for (int r = 0; r < 4; ++r)
        GLOAD_LDS16(wSrc + (size_t)r * NUMD, &Bs[0][wv * 4 + r][0]);
    aSrc0 += BK; aSrc1 += BK; wSrc += (size_t)BK * NUMD;
    for (int kt = 0; kt < NTF; ++kt) {
        const int cur = kt & 1;
        __syncthreads();
        if (kt + 1 < NTF) {
            const int nb = cur ^ 1;
            GLOAD_LDS16(aSrc0, &As[nb][wv * 32][0]);
            GLOAD_LDS16(aSrc1, &As[nb][wv * 32 + 16][0]);
#pragma unroll
            for (int r = 0; r < 4; ++r)
                GLOAD_LDS16(wSrc + (size_t)r * NUMD, &Bs[nb][wv * 4 + r][0]);
            aSrc0 += BK; aSrc1 += BK; wSrc += (size_t)BK * NUMD;
        }
        if (ZDIAG) {
            const int kk = kt * BK;
            if (tid < BK) {
                const int col = kk + tid - n0;
                if (col >= 0 && col < BN) Bs[cur][tid][col] = 0.0f;
            }
            __syncthreads();
        }
#pragma unroll
        for (int g = 0; g < 4; ++g) {
            float4 af[TM];
#pragma unroll
            for (int i = 0; i < TM; ++i) {
                const int m = tr * TM + i;
                af[i] = *(const float4*)&As[cur][m][(g ^ ((m >> 3) & 3)) << 2];
            }
#pragma unroll
            for (int dk = 0; dk < 4; ++dk) {
                float b[TN];
#pragma unroll
                for (int c = 0; c < 4; ++c) {
                    float4 b4 = *(const float4*)&Bs[cur][g * 4 + dk][tc * 4 + 64 * c];
                    b[4*c+0] = b4.x; b[4*c+1] = b4.y; b[4*c+2] = b4.z; b[4*c+3] = b4.w;
                }
#pragma unroll
                for (int i = 0; i < TM; ++i) {
                    const float a = ((const float*)&af[i])[dk];
#pragma unroll
                    for (int j = 0; j < TN; ++j) acc[i][j] = fmaf(a, b[j], acc[i][j]);
                }
            }
        }
    }
    float bv[TN];
#pragma unroll
    for (int c = 0; c < 4; ++c) {
        float4 b4 = *(const float4*)(bias + n0 + tc * 4 + 64 * c);
        bv[4*c+0] = b4.x; bv[4*c+1] = b4.y; bv[4*c+2] = b4.z; bv[4*c+3] = b4.w;
    }
#pragma unroll
    for (int i = 0; i < TM; ++i) {
        const int gm = m0 + tr * TM + i;
        const float* inrow = A + (size_t)gm * NUMD + n0 + tc * 4;
        float* orow = out + (size_t)gm * NUMD + n0 + tc * 4;
#pragma unroll
        for (int c = 0; c < 4; ++c) {
            float4 x = *(const float4*)(inrow + 64 * c);
            float4 o;
            o.x = (acc[i][4*c+0] + bv[4*c+0] > 0.0f) ? x.x : 0.0f;
            o.y = (acc[i][4*c+1] + bv[4*c+1] > 0.0f) ? x.y : 0.0f;
            o.z = (acc[i][4*c+2] + bv[4*c+2] > 0.0f) ? x.z : 0.0f;
            o.w = (acc[i][4*c+3] + bv[4*c+3] > 0.0f) ? x.w : 0.0f;
            *(float4*)(orow + 64 * c) = o;
        }
    }
}

extern "C" void kernel_launch(void* const* d_in, const int* in_sizes, int n_in,
                              void* d_out, int out_size, void* d_ws, size_t ws_size,
                              hipStream_t stream) {
    const float* A    = (const float*)d_in[0];
    const float* W    = (const float*)d_in[1];
    const float* bias = (const float*)d_in[2];
    float* out        = (float*)d_out;
    const int M = in_sizes[0] / NUMD;           // 32768

    const size_t szA  = (size_t)M * NUMD * 2;   // one f16 copy of A
    const size_t need = (2u << 20) + 2 * szA + 1024 + 4 * (size_t)FIXCAP;

    if (ws_size >= need) {
        char* wsb = (char*)d_ws;
        float*    Wt   = (float*)wsb;                              // 1 MiB
        f16*      WtH  = (f16*)(wsb + (1u << 20));                 // 512 KiB
        f16*      WtL  = (f16*)(wsb + (1u << 20) + (512u << 10));  // 512 KiB
        f16*      AH   = (f16*)(wsb + (2u << 20));
        f16*      AL   = (f16*)(wsb + (2u << 20) + szA);
        unsigned* cnt  = (unsigned*)(wsb + (2u << 20) + 2 * szA);
        unsigned* list = cnt + 256;                                // 1 KiB pad

        wprep<<<dim3(NUMD), 256, 0, stream>>>(W, Wt, WtH, WtL, cnt);
        aprep<<<dim3(4096), 256, 0, stream>>>(A, AH, AL, (long)M * 128);
        const int nwg = (M / 128) * (NUMD / 128);
        const int cpx = (nwg % 8 == 0) ? (nwg / 8) : 0;
        li_mfma<<<dim3(nwg), 256, 0, stream>>>(A, AH, AL, WtH, WtL, bias, out,
                                               cnt, list, M, cpx);
        fixup<<<dim3(256), 256, 0, stream>>>(A, Wt, bias, out, cnt, list,
                                             (unsigned)((size_t)M * NUMD));
    } else {
        dim3 grid(M / BM, NUMD / BN);
        const size_t wbytes = (size_t)NUMD * NUMD * sizeof(float);
        if (ws_size >= wbytes) {
            float* Wz = (float*)d_ws;
            zero_diag_kernel<<<dim3(NUMD * NUMD / (4 * 256)), 256, 0, stream>>>(W, Wz);
            li_gemm_fp32<false><<<grid, 256, 0, stream>>>(A, Wz, bias, out, M);
        } else {
            li_gemm_fp32<true><<<grid, 256, 0, stream>>>(A, W, bias, out, M);
        }
    }
}

// Round 9
// 307.961 us; speedup vs baseline: 1.6735x; 1.6735x over previous
//
#include <hip/hip_runtime.h>
#include <stdint.h>

// LateralInhibition: out = inputs * ((inputs @ w1 + b) > 0), w1 = w with zero diag.
// v9 = v8 (PASSED, absmax 0.0) with the epilogue's global atomic hot-spot fixed.
//  - v8 post-mortem: li_mfma 356us with MfmaUtil 5.7 / VALUBusy 8.2 / HBM 5.7%
//    -> ~90% stall, unexplained by BW or barrier latency. Cause: ~30K
//    device-scope atomicAdd to ONE cache line (fix-list counter), return value
//    consumed -> serialized at the home L2 bank (~10-20ns each) ~ 300-600us.
//  - fix: per-block LDS aggregation. Flagged idx -> LDS buffer (LDS atomics,
//    parallel per-CU), ONE global atomicAdd per block (1024 total) reserves a
//    list range, bulk flush. Staging LDS reused as the buffer (dead after
//    K-loop; one barrier before reuse).
// Numerics (v8-proven, absmax 0.0): A*2^12, W*2^13 pre-scale (kills f16
// denormal flush), hi/lo split (lo*2^11), 3x mfma_f32_16x16x32_f16, /2^25
// exact epilogue; |inh|<=1e-3 flagged (error ~1e-6, 1000x margin); fixup
// recomputes flagged elements with the EXACT v4 fp32 op order (k-ascending
// fmaf chain) -> bit-identical to the proven-absmax-0 path.
// Structure: 128x128 tile, 4 waves 2x2, global_load_lds double-buffer
// (conflicts measured 0), XOR swizzle s(row)=(row>>1)&3 both sides,
// XCD-chunked block swizzle, v4 fp32 fallback if ws too small.

#define NUMD 512
#define EPS 1e-3f
#define FIXCAP (1u << 20)
#define LCAP 2048u                   // per-block fix-list capacity (mean ~29)
#define SA 4096.0f                   // 2^12
#define SW 8192.0f                   // 2^13
#define INV_S (1.0f / 33554432.0f)   // 2^-25
#define INV_LO (1.0f / 2048.0f)      // 2^-11

typedef _Float16 f16;
typedef _Float16 f16x8 __attribute__((ext_vector_type(8)));
typedef _Float16 f16x4 __attribute__((ext_vector_type(4)));
typedef float    f32x4 __attribute__((ext_vector_type(4)));

#define GLOAD_LDS16(g, l)                                                      \
  __builtin_amdgcn_global_load_lds(                                            \
      (const __attribute__((address_space(1))) void*)(g),                      \
      (__attribute__((address_space(3))) void*)(l), 16, 0, 0)

// ---------------- pre-pass: W transpose + diag-zero + scaled f16 split ----------------
__global__ __launch_bounds__(256) void wprep(
    const float* __restrict__ W, float* __restrict__ Wt,
    f16* __restrict__ WtH, f16* __restrict__ WtL, unsigned* __restrict__ cnt)
{
    const int n = blockIdx.x;
    if (n == 0 && threadIdx.x == 0) *cnt = 0;
    for (int k = threadIdx.x; k < NUMD; k += 256) {
        float v = W[(size_t)k * NUMD + n];
        if (k == n) v = 0.0f;
        Wt[(size_t)n * NUMD + k] = v;          // unscaled fp32 for fixup
        const float vs = v * SW;
        f16 h = (f16)vs;
        WtH[(size_t)n * NUMD + k] = h;
        WtL[(size_t)n * NUMD + k] = (f16)((vs - (float)h) * 2048.0f);
    }
}

// ---------------- pre-pass: A scaled f16 split (lo additionally x 2^11) ----------------
__global__ __launch_bounds__(256) void aprep(
    const float* __restrict__ A, f16* __restrict__ AH, f16* __restrict__ AL,
    long total4)
{
    for (long i = (long)blockIdx.x * blockDim.x + threadIdx.x; i < total4;
         i += (long)gridDim.x * blockDim.x) {
        float4 a = ((const float4*)A)[i];
        const float* ap = (const float*)&a;
        f16x4 h, lo;
#pragma unroll
        for (int e = 0; e < 4; ++e) {
            const float as = ap[e] * SA;
            f16 hv = (f16)as;
            h[e]  = hv;
            lo[e] = (f16)((as - (float)hv) * 2048.0f);
        }
        ((f16x4*)AH)[i] = h;
        ((f16x4*)AL)[i] = lo;
    }
}

// ---------------- main GEMM (scaled f16 split MFMA) ----------------
__global__ __launch_bounds__(256, 1) void li_mfma(
    const float* __restrict__ A,    // [M,512] fp32 (epilogue gate input)
    const f16* __restrict__ AH, const f16* __restrict__ AL,
    const f16* __restrict__ WtH, const f16* __restrict__ WtL, // [n][k]
    const float* __restrict__ bias,
    float* __restrict__ out,
    unsigned* __restrict__ cnt, unsigned* __restrict__ list,
    int M, int cpx)
{
    // planes: 0=A_hi 1=A_lo 2=B_hi 3=B_lo ; [2 bufs][4 planes][128 rows][32 k] f16
    __shared__ __align__(16) f16 lds[2][4][128][32];   // 64 KiB
    __shared__ unsigned lcnt, lbase;

    const int tid = threadIdx.x;
    const int l   = tid & 63;
    const int wv  = tid >> 6;     // wave 0..3
    const int wr  = wv >> 1;      // wave row 0..1
    const int wc  = wv & 1;       // wave col 0..1
    const int lG  = l >> 4;       // k-chunk group 0..3
    const int lM  = l & 15;       // frag row/col

    int w = blockIdx.x;
    if (cpx) { const int xcd = w & 7, c = w >> 3; w = xcd * cpx + c; }
    const int m0  = (w >> 2) * 128;
    const int n0b = (w & 3) * 128;

    // DMA staging: dest = wave-uniform base + lane*16; lane l covers
    // row rq=(wv*32+(l>>2)), chunk gq=l&3; source pre-swizzled g = gq ^ s(row),
    // s(row) = (row>>1)&3; read side applies the same XOR.
    const int rq  = wv * 32 + (l >> 2);
    const int gq  = l & 3;
    const int s0  = (rq >> 1) & 3;
    const int s1  = ((rq + 16) >> 1) & 3;
    const size_t aOff0 = ((size_t)(m0 + rq)       * NUMD + (size_t)((gq ^ s0) * 8)) * 2;
    const size_t aOff1 = ((size_t)(m0 + rq + 16)  * NUMD + (size_t)((gq ^ s1) * 8)) * 2;
    const size_t bOff0 = ((size_t)(n0b + rq)      * NUMD + (size_t)((gq ^ s0) * 8)) * 2;
    const size_t bOff1 = ((size_t)(n0b + rq + 16) * NUMD + (size_t)((gq ^ s1) * 8)) * 2;
    const char* pAH = (const char*)AH;
    const char* pAL = (const char*)AL;
    const char* pBH = (const char*)WtH;
    const char* pBL = (const char*)WtL;

#define STAGE(nb, ktb) do {                                                    \
    GLOAD_LDS16(pAH + aOff0 + (ktb), &lds[nb][0][wv * 32][0]);                 \
    GLOAD_LDS16(pAH + aOff1 + (ktb), &lds[nb][0][wv * 32 + 16][0]);            \
    GLOAD_LDS16(pAL + aOff0 + (ktb), &lds[nb][1][wv * 32][0]);                 \
    GLOAD_LDS16(pAL + aOff1 + (ktb), &lds[nb][1][wv * 32 + 16][0]);            \
    GLOAD_LDS16(pBH + bOff0 + (ktb), &lds[nb][2][wv * 32][0]);                 \
    GLOAD_LDS16(pBH + bOff1 + (ktb), &lds[nb][2][wv * 32 + 16][0]);            \
    GLOAD_LDS16(pBL + bOff0 + (ktb), &lds[nb][3][wv * 32][0]);                 \
    GLOAD_LDS16(pBL + bOff1 + (ktb), &lds[nb][3][wv * 32 + 16][0]);            \
  } while (0)

    int aRd[4], bRd[4];
#pragma unroll
    for (int f = 0; f < 4; ++f) {
        const int mr = wr * 64 + f * 16 + lM;
        aRd[f] = mr * 64 + ((lG ^ ((mr >> 1) & 3)) << 4);
        const int nr = wc * 64 + f * 16 + lM;
        bRd[f] = nr * 64 + ((lG ^ ((nr >> 1) & 3)) << 4);
    }

    f32x4 accH[4][4], accL[4][4];
#pragma unroll
    for (int i = 0; i < 4; ++i)
#pragma unroll
        for (int j = 0; j < 4; ++j) {
            accH[i][j] = f32x4{0.f, 0.f, 0.f, 0.f};
            accL[i][j] = f32x4{0.f, 0.f, 0.f, 0.f};
        }

    STAGE(0, 0);

    const int NT = NUMD / 32;   // 16
    for (int kt = 0; kt < NT; ++kt) {
        const int cur = kt & 1;
        __syncthreads();                       // drains tile-kt DMAs (vmcnt0+barrier)
        if (kt + 1 < NT) STAGE(cur ^ 1, (size_t)(kt + 1) * 64);

        const char* PAH = (const char*)&lds[cur][0][0][0];
        const char* PAL = (const char*)&lds[cur][1][0][0];
        const char* PBH = (const char*)&lds[cur][2][0][0];
        const char* PBL = (const char*)&lds[cur][3][0][0];

        f16x8 bh[4], bl[4];
#pragma unroll
        for (int fj = 0; fj < 4; ++fj) {
            bh[fj] = *(const f16x8*)(PBH + bRd[fj]);
            bl[fj] = *(const f16x8*)(PBL + bRd[fj]);
        }
#pragma unroll
        for (int fi = 0; fi < 4; ++fi) {
            const f16x8 ah = *(const f16x8*)(PAH + aRd[fi]);
            const f16x8 al = *(const f16x8*)(PAL + aRd[fi]);
#pragma unroll
            for (int fj = 0; fj < 4; ++fj) {
                accH[fi][fj] = __builtin_amdgcn_mfma_f32_16x16x32_f16(ah, bh[fj], accH[fi][fj], 0, 0, 0);
                accL[fi][fj] = __builtin_amdgcn_mfma_f32_16x16x32_f16(ah, bl[fj], accL[fi][fj], 0, 0, 0);
                accL[fi][fj] = __builtin_amdgcn_mfma_f32_16x16x32_f16(al, bh[fj], accL[fi][fj], 0, 0, 0);
            }
        }
    }

    // ---- staging LDS is dead; reuse as per-block fix-list buffer
    __syncthreads();
    unsigned* lbuf = (unsigned*)&lds[0][0][0][0];
    if (tid == 0) lcnt = 0;
    __syncthreads();

    // epilogue: C/D layout col=lane&15, row=(lane>>4)*4+reg (m89-verified)
#pragma unroll
    for (int fj = 0; fj < 4; ++fj) {
        const int n = n0b + wc * 64 + fj * 16 + lM;
        const float bvj = bias[n];
#pragma unroll
        for (int fi = 0; fi < 4; ++fi) {
            const int mb = m0 + wr * 64 + fi * 16 + lG * 4;
#pragma unroll
            for (int r = 0; r < 4; ++r) {
                const size_t idx = (size_t)(mb + r) * NUMD + n;
                const float inh =
                    (accH[fi][fj][r] + accL[fi][fj][r] * INV_LO) * INV_S + bvj;
                const float x = A[idx];
                out[idx] = (inh > 0.0f) ? x : 0.0f;
                if (__builtin_fabsf(inh) <= EPS) {
                    unsigned p = atomicAdd(&lcnt, 1u);   // LDS atomic (per-CU)
                    if (p < LCAP) lbuf[p] = (unsigned)idx;
                }
            }
        }
    }

    // one global atomic per block, then bulk flush
    __syncthreads();
    if (tid == 0) {
        unsigned nf = lcnt; if (nf > LCAP) nf = LCAP;
        lbase = atomicAdd(cnt, nf);
    }
    __syncthreads();
    {
        unsigned nf = lcnt; if (nf > LCAP) nf = LCAP;
        for (unsigned i = tid; i < nf; i += 256) {
            const unsigned p = lbase + i;
            if (p < FIXCAP) list[p] = lbuf[i];
        }
    }
#undef STAGE
}

// ------- fixup: exact fp32 recompute, BIT-IDENTICAL order to the proven v4 path -------
__global__ __launch_bounds__(256) void fixup(
    const float* __restrict__ A, const float* __restrict__ Wt, // Wt[n][k] diag-zeroed
    const float* __restrict__ bias, float* __restrict__ out,
    const unsigned* __restrict__ cnt, const unsigned* __restrict__ list,
    unsigned total)
{
    unsigned nfix = *cnt;
    if (nfix > FIXCAP) nfix = FIXCAP;
    for (unsigned e = blockIdx.x * blockDim.x + threadIdx.x; e < nfix;
         e += gridDim.x * blockDim.x) {
        const unsigned code = list[e];
        if (code >= total) continue;           // safety guard
        const int n = (int)(code & 511);
        const float* ar = A  + (size_t)(code >> 9) * NUMD;
        const float* wr = Wt + (size_t)n * NUMD;
        float s = 0.0f;
#pragma unroll 8
        for (int k = 0; k < NUMD; ++k)
            s = fmaf(ar[k], wr[k], s);         // strict k-ascending chain
        const float inh = s + bias[n];
        out[code] = (inh > 0.0f) ? A[code] : 0.0f;
    }
}

// ---------------- fallback: v4 exact fp32 path (proven 205us) ----------------
#define BM 128
#define BN 256
#define BK 16
#define TM 8
#define TN 16
#define NTF (NUMD / BK)

__global__ __launch_bounds__(256) void zero_diag_kernel(
    const float* __restrict__ W, float* __restrict__ Wz)
{
    const int f = (int)(blockIdx.x * blockDim.x + threadIdx.x) * 4;
    const int row = f >> 9, col0 = f & 511;
    float4 v = *(const float4*)(W + f);
    if (row == col0 + 0) v.x = 0.0f;
    if (row == col0 + 1) v.y = 0.0f;
    if (row == col0 + 2) v.z = 0.0f;
    if (row == col0 + 3) v.w = 0.0f;
    *(float4*)(Wz + f) = v;
}

template<bool ZDIAG>
__global__ __launch_bounds__(256, 1) void li_gemm_fp32(
    const float* __restrict__ A, const float* __restrict__ Wm,
    const float* __restrict__ bias, float* __restrict__ out, int M)
{
    __shared__ __align__(16) float As[2][BM][BK];
    __shared__ __align__(16) float Bs[2][BK][BN];
    const int tid = threadIdx.x, lane = tid & 63, wv = tid >> 6;
    const int tc = tid & 15, tr = tid >> 4;
    const int m0 = blockIdx.x * BM, n0 = blockIdx.y * BN;
    const int am0 = wv * 32 + (lane >> 2), am1 = am0 + 16;
    const int q0 = ((lane & 3) ^ ((am0 >> 3) & 3)) << 2;
    const int q1 = ((lane & 3) ^ ((am1 >> 3) & 3)) << 2;
    const float* aSrc0 = A + (size_t)(m0 + am0) * NUMD + q0;
    const float* aSrc1 = A + (size_t)(m0 + am1) * NUMD + q1;
    const float* wSrc = Wm + (size_t)(wv * 4) * NUMD + n0 + lane * 4;
    float acc[TM][TN];
#pragma unroll
    for (int i = 0; i < TM; ++i)
#pragma unroll
        for (int j = 0; j < TN; ++j) acc[i][j] = 0.0f;
    GLOAD_LDS16(aSrc0, &As[0][wv * 32][0]);
    GLOAD_LDS16(aSrc1, &As[0][wv * 32 + 16][0]);
#pragma unroll
    for (int r = 0; r < 4; ++r)
        GLOAD_LDS16(wSrc + (size_t)r * NUMD, &Bs[0][wv * 4 + r][0]);
    aSrc0 += BK; aSrc1 += BK; wSrc += (size_t)BK * NUMD;
    for (int kt = 0; kt < NTF; ++kt) {
        const int cur = kt & 1;
        __syncthreads();
        if (kt + 1 < NTF) {
            const int nb = cur ^ 1;
            GLOAD_LDS16(aSrc0, &As[nb][wv * 32][0]);
            GLOAD_LDS16(aSrc1, &As[nb][wv * 32 + 16][0]);
#pragma unroll
            for (int r = 0; r < 4; ++r)
                GLOAD_LDS16(wSrc + (size_t)r * NUMD, &Bs[nb][wv * 4 + r][0]);
            aSrc0 += BK; aSrc1 += BK; wSrc += (size_t)BK * NUMD;
        }
        if (ZDIAG) {
            const int kk = kt * BK;
            if (tid < BK) {
                const int col = kk + tid - n0;
                if (col >= 0 && col < BN) Bs[cur][tid][col] = 0.0f;
            }
            __syncthreads();
        }
#pragma unroll
        for (int g = 0; g < 4; ++g) {
            float4 af[TM];
#pragma unroll
            for (int i = 0; i < TM; ++i) {
                const int m = tr * TM + i;
                af[i] = *(const float4*)&As[cur][m][(g ^ ((m >> 3) & 3)) << 2];
            }
#pragma unroll
            for (int dk = 0; dk < 4; ++dk) {
                float b[TN];
#pragma unroll
                for (int c = 0; c < 4; ++c) {
                    float4 b4 = *(const float4*)&Bs[cur][g * 4 + dk][tc * 4 + 64 * c];
                    b[4*c+0] = b4.x; b[4*c+1] = b4.y; b[4*c+2] = b4.z; b[4*c+3] = b4.w;
                }
#pragma unroll
                for (int i = 0; i < TM; ++i) {
                    const float a = ((const float*)&af[i])[dk];
#pragma unroll
                    for (int j = 0; j < TN; ++j) acc[i][j] = fmaf(a, b[j], acc[i][j]);
                }
            }
        }
    }
    float bv[TN];
#pragma unroll
    for (int c = 0; c < 4; ++c) {
        float4 b4 = *(const float4*)(bias + n0 + tc * 4 + 64 * c);
        bv[4*c+0] = b4.x; bv[4*c+1] = b4.y; bv[4*c+2] = b4.z; bv[4*c+3] = b4.w;
    }
#pragma unroll
    for (int i = 0; i < TM; ++i) {
        const int gm = m0 + tr * TM + i;
        const float* inrow = A + (size_t)gm * NUMD + n0 + tc * 4;
        float* orow = out + (size_t)gm * NUMD + n0 + tc * 4;
#pragma unroll
        for (int c = 0; c < 4; ++c) {
            float4 x = *(const float4*)(inrow + 64 * c);
            float4 o;
            o.x = (acc[i][4*c+0] + bv[4*c+0] > 0.0f) ? x.x : 0.0f;
            o.y = (acc[i][4*c+1] + bv[4*c+1] > 0.0f) ? x.y : 0.0f;
            o.z = (acc[i][4*c+2] + bv[4*c+2] > 0.0f) ? x.z : 0.0f;
            o.w = (acc[i][4*c+3] + bv[4*c+3] > 0.0f) ? x.w : 0.0f;
            *(float4*)(orow + 64 * c) = o;
        }
    }
}

extern "C" void kernel_launch(void* const* d_in, const int* in_sizes, int n_in,
                              void* d_out, int out_size, void* d_ws, size_t ws_size,
                              hipStream_t stream) {
    const float* A    = (const float*)d_in[0];
    const float* W    = (const float*)d_in[1];
    const float* bias = (const float*)d_in[2];
    float* out        = (float*)d_out;
    const int M = in_sizes[0] / NUMD;           // 32768

    const size_t szA  = (size_t)M * NUMD * 2;   // one f16 copy of A
    const size_t need = (2u << 20) + 2 * szA + 1024 + 4 * (size_t)FIXCAP;

    if (ws_size >= need) {
        char* wsb = (char*)d_ws;
        float*    Wt   = (float*)wsb;                              // 1 MiB
        f16*      WtH  = (f16*)(wsb + (1u << 20));                 // 512 KiB
        f16*      WtL  = (f16*)(wsb + (1u << 20) + (512u << 10));  // 512 KiB
        f16*      AH   = (f16*)(wsb + (2u << 20));
        f16*      AL   = (f16*)(wsb + (2u << 20) + szA);
        unsigned* cnt  = (unsigned*)(wsb + (2u << 20) + 2 * szA);
        unsigned* list = cnt + 256;                                // 1 KiB pad

        wprep<<<dim3(NUMD), 256, 0, stream>>>(W, Wt, WtH, WtL, cnt);
        aprep<<<dim3(4096), 256, 0, stream>>>(A, AH, AL, (long)M * 128);
        const int nwg = (M / 128) * (NUMD / 128);
        const int cpx = (nwg % 8 == 0) ? (nwg / 8) : 0;
        li_mfma<<<dim3(nwg), 256, 0, stream>>>(A, AH, AL, WtH, WtL, bias, out,
                                               cnt, list, M, cpx);
        fixup<<<dim3(256), 256, 0, stream>>>(A, Wt, bias, out, cnt, list,
                                             (unsigned)((size_t)M * NUMD));
    } else {
        dim3 grid(M / BM, NUMD / BN);
        const size_t wbytes = (size_t)NUMD * NUMD * sizeof(float);
        if (ws_size >= wbytes) {
            float* Wz = (float*)d_ws;
            zero_diag_kernel<<<dim3(NUMD * NUMD / (4 * 256)), 256, 0, stream>>>(W, Wz);
            li_gemm_fp32<false><<<grid, 256, 0, stream>>>(A, Wz, bias, out, M);
        } else {
            li_gemm_fp32<true><<<grid, 256, 0, stream>>>(A, W, bias, out, M);
        }
    }
}

// Round 10
// 302.128 us; speedup vs baseline: 1.7059x; 1.0193x over previous
//
#include <hip/hip_runtime.h>
#include <stdint.h>

// LateralInhibition: out = inputs * ((inputs @ w1 + b) > 0), w1 = w with zero diag.
// v10 = v9 (PASSED, 308us; li_mfma 161us) + counted-vmcnt deep pipeline.
//  - v9 post-mortem: li_mfma MfmaUtil 12.7 / VALUBusy 18 / HBM 15% / occ ~1
//    block/CU -> per-k-tile vmcnt(0) drain exposes ~400cyc of HBM latency
//    every tile with no second block to hide it (T3/T4 diagnosis).
//  - fix: 3 LDS buffers, 2-deep prefetch. Loop: s_waitcnt vmcnt(8) (own tile-t
//    loads done, t+1 in flight - NEVER drain to 0), raw s_barrier +
//    sched_barrier(0), issue STAGE(t+2) into buf[(t+2)%3] (= buf[(t-1)%3],
//    safe: barrier(t) => all waves finished compute(t-1)). DMA latency spans
//    2 compute phases. s_setprio(1) around MFMA cluster (T5).
//  - wprep+aprep fused into one launch.
// Numerics (v8/v9-proven, absmax 0.0): A*2^12, W*2^13 pre-scale (kills f16
// denormal flush), hi/lo split (lo*2^11), 3x mfma_f32_16x16x32_f16, /2^25
// exact epilogue; |inh|<=1e-3 flagged via LDS-aggregated list (v9's atomic
// fix); fixup recomputes flagged elements with the EXACT v4 fp32 op order
// (k-ascending fmaf chain) -> bit-identical to the proven-absmax-0 path.

#define NUMD 512
#define EPS 1e-3f
#define FIXCAP (1u << 20)
#define LCAP 2048u                   // per-block fix-list capacity (mean ~29)
#define SA 4096.0f                   // 2^12
#define SW 8192.0f                   // 2^13
#define INV_S (1.0f / 33554432.0f)   // 2^-25
#define INV_LO (1.0f / 2048.0f)      // 2^-11

typedef _Float16 f16;
typedef _Float16 f16x8 __attribute__((ext_vector_type(8)));
typedef _Float16 f16x4 __attribute__((ext_vector_type(4)));
typedef float    f32x4 __attribute__((ext_vector_type(4)));

#define GLOAD_LDS16(g, l)                                                      \
  __builtin_amdgcn_global_load_lds(                                            \
      (const __attribute__((address_space(1))) void*)(g),                      \
      (__attribute__((address_space(3))) void*)(l), 16, 0, 0)

// -------- fused pre-pass: blocks 0..511 = W prep; 512.. = A split --------
__global__ __launch_bounds__(256) void prep(
    const float* __restrict__ W, float* __restrict__ Wt,
    f16* __restrict__ WtH, f16* __restrict__ WtL, unsigned* __restrict__ cnt,
    const float* __restrict__ A, f16* __restrict__ AH, f16* __restrict__ AL,
    long total4, int nAblocks)
{
    const int b = blockIdx.x;
    if (b < NUMD) {
        const int n = b;
        if (n == 0 && threadIdx.x == 0) *cnt = 0;
        for (int k = threadIdx.x; k < NUMD; k += 256) {
            float v = W[(size_t)k * NUMD + n];
            if (k == n) v = 0.0f;
            Wt[(size_t)n * NUMD + k] = v;      // unscaled fp32 for fixup
            const float vs = v * SW;
            f16 h = (f16)vs;
            WtH[(size_t)n * NUMD + k] = h;
            WtL[(size_t)n * NUMD + k] = (f16)((vs - (float)h) * 2048.0f);
        }
    } else {
        const long ab = b - NUMD;
        for (long i = ab * blockDim.x + threadIdx.x; i < total4;
             i += (long)nAblocks * blockDim.x) {
            float4 a = ((const float4*)A)[i];
            const float* ap = (const float*)&a;
            f16x4 h, lo;
#pragma unroll
            for (int e = 0; e < 4; ++e) {
                const float as = ap[e] * SA;
                f16 hv = (f16)as;
                h[e]  = hv;
                lo[e] = (f16)((as - (float)hv) * 2048.0f);
            }
            ((f16x4*)AH)[i] = h;
            ((f16x4*)AL)[i] = lo;
        }
    }
}

// ---------------- main GEMM (scaled f16 split MFMA, deep pipeline) ----------------
__global__ __launch_bounds__(256, 1) void li_mfma(
    const float* __restrict__ A,    // [M,512] fp32 (epilogue gate input)
    const f16* __restrict__ AH, const f16* __restrict__ AL,
    const f16* __restrict__ WtH, const f16* __restrict__ WtL, // [n][k]
    const float* __restrict__ bias,
    float* __restrict__ out,
    unsigned* __restrict__ cnt, unsigned* __restrict__ list,
    int M, int cpx)
{
    // 3 double... triple-buffered: [3 bufs][4 planes][128 rows][32 k] f16 = 96 KiB
    __shared__ __align__(16) f16 lds[3][4][128][32];
    __shared__ unsigned lcnt, lbase;

    const int tid = threadIdx.x;
    const int l   = tid & 63;
    const int wv  = tid >> 6;     // wave 0..3
    const int wr  = wv >> 1;      // wave row 0..1
    const int wc  = wv & 1;       // wave col 0..1
    const int lG  = l >> 4;       // k-chunk group 0..3
    const int lM  = l & 15;       // frag row/col

    int w = blockIdx.x;
    if (cpx) { const int xcd = w & 7, c = w >> 3; w = xcd * cpx + c; }
    const int m0  = (w >> 2) * 128;
    const int n0b = (w & 3) * 128;

    // DMA staging: dest = wave-uniform base + lane*16; lane l covers
    // row rq=(wv*32+(l>>2)), chunk gq=l&3; source pre-swizzled g = gq ^ s(row),
    // s(row) = (row>>1)&3; read side applies the same XOR.
    const int rq  = wv * 32 + (l >> 2);
    const int gq  = l & 3;
    const int s0  = (rq >> 1) & 3;
    const int s1  = ((rq + 16) >> 1) & 3;
    const size_t aOff0 = ((size_t)(m0 + rq)       * NUMD + (size_t)((gq ^ s0) * 8)) * 2;
    const size_t aOff1 = ((size_t)(m0 + rq + 16)  * NUMD + (size_t)((gq ^ s1) * 8)) * 2;
    const size_t bOff0 = ((size_t)(n0b + rq)      * NUMD + (size_t)((gq ^ s0) * 8)) * 2;
    const size_t bOff1 = ((size_t)(n0b + rq + 16) * NUMD + (size_t)((gq ^ s1) * 8)) * 2;
    const char* pAH = (const char*)AH;
    const char* pAL = (const char*)AL;
    const char* pBH = (const char*)WtH;
    const char* pBL = (const char*)WtL;

#define STAGE(nb, ktb) do {                                                    \
    GLOAD_LDS16(pAH + aOff0 + (ktb), &lds[nb][0][wv * 32][0]);                 \
    GLOAD_LDS16(pAH + aOff1 + (ktb), &lds[nb][0][wv * 32 + 16][0]);            \
    GLOAD_LDS16(pAL + aOff0 + (ktb), &lds[nb][1][wv * 32][0]);                 \
    GLOAD_LDS16(pAL + aOff1 + (ktb), &lds[nb][1][wv * 32 + 16][0]);            \
    GLOAD_LDS16(pBH + bOff0 + (ktb), &lds[nb][2][wv * 32][0]);                 \
    GLOAD_LDS16(pBH + bOff1 + (ktb), &lds[nb][2][wv * 32 + 16][0]);            \
    GLOAD_LDS16(pBL + bOff0 + (ktb), &lds[nb][3][wv * 32][0]);                 \
    GLOAD_LDS16(pBL + bOff1 + (ktb), &lds[nb][3][wv * 32 + 16][0]);            \
  } while (0)

    int aRd[4], bRd[4];
#pragma unroll
    for (int f = 0; f < 4; ++f) {
        const int mr = wr * 64 + f * 16 + lM;
        aRd[f] = mr * 64 + ((lG ^ ((mr >> 1) & 3)) << 4);
        const int nr = wc * 64 + f * 16 + lM;
        bRd[f] = nr * 64 + ((lG ^ ((nr >> 1) & 3)) << 4);
    }

    f32x4 accH[4][4], accL[4][4];
#pragma unroll
    for (int i = 0; i < 4; ++i)
#pragma unroll
        for (int j = 0; j < 4; ++j) {
            accH[i][j] = f32x4{0.f, 0.f, 0.f, 0.f};
            accL[i][j] = f32x4{0.f, 0.f, 0.f, 0.f};
        }

    // prologue: 2 tiles in flight (16 outstanding VMEM/wave)
    STAGE(0, 0);
    STAGE(1, 64);

    const int NT = NUMD / 32;   // 16
    for (int kt = 0; kt < NT; ++kt) {
        const int cur = kt % 3;
        // counted wait: own tile-kt loads (oldest 8) done; tile kt+1's 8 stay
        // in flight across the barrier. Never drain to 0 in the loop (T4).
        if (kt < NT - 1) asm volatile("s_waitcnt vmcnt(8)" ::: "memory");
        else             asm volatile("s_waitcnt vmcnt(0)" ::: "memory");
        __builtin_amdgcn_s_barrier();
        __builtin_amdgcn_sched_barrier(0);
        // issue tile kt+2 into buf[(kt+2)%3] = buf[(kt-1)%3]: safe, barrier
        // above proves all waves finished compute(kt-1).
        if (kt + 2 < NT) STAGE((kt + 2) % 3, (size_t)(kt + 2) * 64);
        __builtin_amdgcn_sched_barrier(0);

        const char* PAH = (const char*)&lds[cur][0][0][0];
        const char* PAL = (const char*)&lds[cur][1][0][0];
        const char* PBH = (const char*)&lds[cur][2][0][0];
        const char* PBL = (const char*)&lds[cur][3][0][0];

        f16x8 bh[4], bl[4];
#pragma unroll
        for (int fj = 0; fj < 4; ++fj) {
            bh[fj] = *(const f16x8*)(PBH + bRd[fj]);
            bl[fj] = *(const f16x8*)(PBL + bRd[fj]);
        }
        __builtin_amdgcn_s_setprio(1);
#pragma unroll
        for (int fi = 0; fi < 4; ++fi) {
            const f16x8 ah = *(const f16x8*)(PAH + aRd[fi]);
            const f16x8 al = *(const f16x8*)(PAL + aRd[fi]);
#pragma unroll
            for (int fj = 0; fj < 4; ++fj) {
                accH[fi][fj] = __builtin_amdgcn_mfma_f32_16x16x32_f16(ah, bh[fj], accH[fi][fj], 0, 0, 0);
                accL[fi][fj] = __builtin_amdgcn_mfma_f32_16x16x32_f16(ah, bl[fj], accL[fi][fj], 0, 0, 0);
                accL[fi][fj] = __builtin_amdgcn_mfma_f32_16x16x32_f16(al, bh[fj], accL[fi][fj], 0, 0, 0);
            }
        }
        __builtin_amdgcn_s_setprio(0);
    }

    // ---- staging LDS is dead; reuse as per-block fix-list buffer
    __syncthreads();
    unsigned* lbuf = (unsigned*)&lds[0][0][0][0];
    if (tid == 0) lcnt = 0;
    __syncthreads();

    // epilogue: C/D layout col=lane&15, row=(lane>>4)*4+reg (m89-verified)
#pragma unroll
    for (int fj = 0; fj < 4; ++fj) {
        const int n = n0b + wc * 64 + fj * 16 + lM;
        const float bvj = bias[n];
#pragma unroll
        for (int fi = 0; fi < 4; ++fi) {
            const int mb = m0 + wr * 64 + fi * 16 + lG * 4;
#pragma unroll
            for (int r = 0; r < 4; ++r) {
                const size_t idx = (size_t)(mb + r) * NUMD + n;
                const float inh =
                    (accH[fi][fj][r] + accL[fi][fj][r] * INV_LO) * INV_S + bvj;
                const float x = A[idx];
                out[idx] = (inh > 0.0f) ? x : 0.0f;
                if (__builtin_fabsf(inh) <= EPS) {
                    unsigned p = atomicAdd(&lcnt, 1u);   // LDS atomic (per-CU)
                    if (p < LCAP) lbuf[p] = (unsigned)idx;
                }
            }
        }
    }

    // one global atomic per block, then bulk flush
    __syncthreads();
    if (tid == 0) {
        unsigned nf = lcnt; if (nf > LCAP) nf = LCAP;
        lbase = atomicAdd(cnt, nf);
    }
    __syncthreads();
    {
        unsigned nf = lcnt; if (nf > LCAP) nf = LCAP;
        for (unsigned i = tid; i < nf; i += 256) {
            const unsigned p = lbase + i;
            if (p < FIXCAP) list[p] = lbuf[i];
        }
    }
#undef STAGE
}

// ------- fixup: exact fp32 recompute, BIT-IDENTICAL order to the proven v4 path -------
__global__ __launch_bounds__(256) void fixup(
    const float* __restrict__ A, const float* __restrict__ Wt, // Wt[n][k] diag-zeroed
    const float* __restrict__ bias, float* __restrict__ out,
    const unsigned* __restrict__ cnt, const unsigned* __restrict__ list,
    unsigned total)
{
    unsigned nfix = *cnt;
    if (nfix > FIXCAP) nfix = FIXCAP;
    for (unsigned e = blockIdx.x * blockDim.x + threadIdx.x; e < nfix;
         e += gridDim.x * blockDim.x) {
        const unsigned code = list[e];
        if (code >= total) continue;           // safety guard
        const int n = (int)(code & 511);
        const float* ar = A  + (size_t)(code >> 9) * NUMD;
        const float* wr = Wt + (size_t)n * NUMD;
        float s = 0.0f;
#pragma unroll 8
        for (int k = 0; k < NUMD; ++k)
            s = fmaf(ar[k], wr[k], s);         // strict k-ascending chain
        const float inh = s + bias[n];
        out[code] = (inh > 0.0f) ? A[code] : 0.0f;
    }
}

// ---------------- fallback: v4 exact fp32 path (proven 205us) ----------------
#define BM 128
#define BN 256
#define BK 16
#define TM 8
#define TN 16
#define NTF (NUMD / BK)

__global__ __launch_bounds__(256) void zero_diag_kernel(
    const float* __restrict__ W, float* __restrict__ Wz)
{
    const int f = (int)(blockIdx.x * blockDim.x + threadIdx.x) * 4;
    const int row = f >> 9, col0 = f & 511;
    float4 v = *(const float4*)(W + f);
    if (row == col0 + 0) v.x = 0.0f;
    if (row == col0 + 1) v.y = 0.0f;
    if (row == col0 + 2) v.z = 0.0f;
    if (row == col0 + 3) v.w = 0.0f;
    *(float4*)(Wz + f) = v;
}

template<bool ZDIAG>
__global__ __launch_bounds__(256, 1) void li_gemm_fp32(
    const float* __restrict__ A, const float* __restrict__ Wm,
    const float* __restrict__ bias, float* __restrict__ out, int M)
{
    __shared__ __align__(16) float As[2][BM][BK];
    __shared__ __align__(16) float Bs[2][BK][BN];
    const int tid = threadIdx.x, lane = tid & 63, wv = tid >> 6;
    const int tc = tid & 15, tr = tid >> 4;
    const int m0 = blockIdx.x * BM, n0 = blockIdx.y * BN;
    const int am0 = wv * 32 + (lane >> 2), am1 = am0 + 16;
    const int q0 = ((lane & 3) ^ ((am0 >> 3) & 3)) << 2;
    const int q1 = ((lane & 3) ^ ((am1 >> 3) & 3)) << 2;
    const float* aSrc0 = A + (size_t)(m0 + am0) * NUMD + q0;
    const float* aSrc1 = A + (size_t)(m0 + am1) * NUMD + q1;
    const float* wSrc = Wm + (size_t)(wv * 4) * NUMD + n0 + lane * 4;
    float acc[TM][TN];
#pragma unroll
    for (int i = 0; i < TM; ++i)
#pragma unroll
        for (int j = 0; j < TN; ++j) acc[i][j] = 0.0f;
    GLOAD_LDS16(aSrc0, &As[0][wv * 32][0]);
    GLOAD_LDS16(aSrc1, &As[0][wv * 32 + 16][0]);
#pragma unroll
    for (int r = 0; r < 4; ++r)
        GLOAD_LDS16(wSrc + (size_t)r * NUMD, &Bs[0][wv * 4 + r][0]);
    aSrc0 += BK; aSrc1 += BK; wSrc += (size_t)BK * NUMD;
    for (int kt = 0; kt < NTF; ++kt) {
        const int cur = kt & 1;
        __syncthreads();
        if (kt + 1 < NTF) {
            const int nb = cur ^ 1;
            GLOAD_LDS16(aSrc0, &As[nb][wv * 32][0]);
            GLOAD_LDS16(aSrc1, &As[nb][wv * 32 + 16][0]);
#pragma unroll
            for (int r = 0; r < 4; ++r)
                GLOAD_LDS16(wSrc + (size_t)r * NUMD, &Bs[nb][wv * 4 + r][0]);
            aSrc0 += BK; aSrc1 += BK; wSrc += (size_t)BK * NUMD;
        }
        if (ZDIAG) {
            const int kk = kt * BK;
            if (tid < BK) {
                const int col = kk + tid - n0;
                if (col >= 0 && col < BN) Bs[cur][tid][col] = 0.0f;
            }
            __syncthreads();
        }
#pragma unroll
        for (int g = 0; g < 4; ++g) {
            float4 af[TM];
#pragma unroll
            for (int i = 0; i < TM; ++i) {
                const int m = tr * TM + i;
                af[i] = *(const float4*)&As[cur][m][(g ^ ((m >> 3) & 3)) << 2];
            }
#pragma unroll
            for (int dk = 0; dk < 4; ++dk) {
                float b[TN];
#pragma unroll
                for (int c = 0; c < 4; ++c) {
                    float4 b4 = *(const float4*)&Bs[cur][g * 4 + dk][tc * 4 + 64 * c];
                    b[4*c+0] = b4.x; b[4*c+1] = b4.y; b[4*c+2] = b4.z; b[4*c+3] = b4.w;
                }
#pragma unroll
                for (int i = 0; i < TM; ++i) {
                    const float a = ((const float*)&af[i])[dk];
#pragma unroll
                    for (int j = 0; j < TN; ++j) acc[i][j] = fmaf(a, b[j], acc[i][j]);
                }
            }
        }
    }
    float bv[TN];
#pragma unroll
    for (int c = 0; c < 4; ++c) {
        float4 b4 = *(const float4*)(bias + n0 + tc * 4 + 64 * c);
        bv[4*c+0] = b4.x; bv[4*c+1] = b4.y; bv[4*c+2] = b4.z; bv[4*c+3] = b4.w;
    }
#pragma unroll
    for (int i = 0; i < TM; ++i) {
        const int gm = m0 + tr * TM + i;
        const float* inrow = A + (size_t)gm * NUMD + n0 + tc * 4;
        float* orow = out + (size_t)gm * NUMD + n0 + tc * 4;
#pragma unroll
        for (int c = 0; c < 4; ++c) {
            float4 x = *(const float4*)(inrow + 64 * c);
            float4 o;
            o.x = (acc[i][4*c+0] + bv[4*c+0] > 0.0f) ? x.x : 0.0f;
            o.y = (acc[i][4*c+1] + bv[4*c+1] > 0.0f) ? x.y : 0.0f;
            o.z = (acc[i][4*c+2] + bv[4*c+2] > 0.0f) ? x.z : 0.0f;
            o.w = (acc[i][4*c+3] + bv[4*c+3] > 0.0f) ? x.w : 0.0f;
            *(float4*)(orow + 64 * c) = o;
        }
    }
}

extern "C" void kernel_launch(void* const* d_in, const int* in_sizes, int n_in,
                              void* d_out, int out_size, void* d_ws, size_t ws_size,
                              hipStream_t stream) {
    const float* A    = (const float*)d_in[0];
    const float* W    = (const float*)d_in[1];
    const float* bias = (const float*)d_in[2];
    float* out        = (float*)d_out;
    const int M = in_sizes[0] / NUMD;           // 32768

    const size_t szA  = (size_t)M * NUMD * 2;   // one f16 copy of A
    const size_t need = (2u << 20) + 2 * szA + 1024 + 4 * (size_t)FIXCAP;

    if (ws_size >= need) {
        char* wsb = (char*)d_ws;
        float*    Wt   = (float*)wsb;                              // 1 MiB
        f16*      WtH  = (f16*)(wsb + (1u << 20));                 // 512 KiB
        f16*      WtL  = (f16*)(wsb + (1u << 20) + (512u << 10));  // 512 KiB
        f16*      AH   = (f16*)(wsb + (2u << 20));
        f16*      AL   = (f16*)(wsb + (2u << 20) + szA);
        unsigned* cnt  = (unsigned*)(wsb + (2u << 20) + 2 * szA);
        unsigned* list = cnt + 256;                                // 1 KiB pad

        const int nAblocks = 4096;
        prep<<<dim3(NUMD + nAblocks), 256, 0, stream>>>(
            W, Wt, WtH, WtL, cnt, A, AH, AL, (long)M * 128, nAblocks);
        const int nwg = (M / 128) * (NUMD / 128);
        const int cpx = (nwg % 8 == 0) ? (nwg / 8) : 0;
        li_mfma<<<dim3(nwg), 256, 0, stream>>>(A, AH, AL, WtH, WtL, bias, out,
                                               cnt, list, M, cpx);
        fixup<<<dim3(256), 256, 0, stream>>>(A, Wt, bias, out, cnt, list,
                                             (unsigned)((size_t)M * NUMD));
    } else {
        dim3 grid(M / BM, NUMD / BN);
        const size_t wbytes = (size_t)NUMD * NUMD * sizeof(float);
        if (ws_size >= wbytes) {
            float* Wz = (float*)d_ws;
            zero_diag_kernel<<<dim3(NUMD * NUMD / (4 * 256)), 256, 0, stream>>>(W, Wz);
            li_gemm_fp32<false><<<grid, 256, 0, stream>>>(A, Wz, bias, out, M);
        } else {
            li_gemm_fp32<true><<<grid, 256, 0, stream>>>(A, W, bias, out, M);
        }
    }
}

// Round 11
// 241.704 us; speedup vs baseline: 2.1323x; 1.2500x over previous
//
#include <hip/hip_runtime.h>
#include <stdint.h>

// LateralInhibition: out = inputs * ((inputs @ w1 + b) > 0), w1 = w with zero diag.
// v11 = v9/v10 with the occupancy limiter removed + contiguous DMA.
//  - v10 post-mortem: deep pipeline NEUTRAL (158us). All pipes 13-17% idle at
//    occupancy 11% = 1 wave/SIMD: accH+accL = 128 acc regs + 180 VGPR > 256
//    (unified file) caps 1 wave/SIMD; lockstep waves -> nothing hides latency.
//  - fix 1: SINGLE accumulator. lo residuals UNSCALED (no 2^11): all three
//    products (ah*bh, ah*bl, al*bh) at scale 2^25 into one acc[4][4].
//    Error: lo-cast flush <=1.5e-8, omitted lo*lo <=7.4e-5, MFMA denorm
//    <=8.5e-7 -- all << EPS=1e-3. ~214 regs -> 2 waves/SIMD, 2 blocks/CU.
//  - fix 2: operands pre-tiled [slab][kt][128][32] f16 (8KB contiguous tiles),
//    bank-XOR (p = c ^ ((row>>1)&3)) baked in at prep-write time -> each
//    global_load_lds reads 1KB contiguous; LDS-read XOR unchanged.
//  - fix 3: back to v9's __syncthreads 2-buffer schedule (v10 pipeline was
//    neutral; co-resident block now covers the barrier drain).
// Numerics otherwise v8/v9-proven (absmax 0.0): A*2^12, W*2^13 pre-scale,
// /2^25 exact epilogue; LDS-aggregated fix-list (v9 atomic fix); fixup with
// EXACT v4 fp32 op order (k-ascending fmaf) -> bit-identical signs.

#define NUMD 512
#define EPS 1e-3f
#define FIXCAP (1u << 20)
#define LCAP 2048u
#define SA 4096.0f                   // 2^12
#define SW 8192.0f                   // 2^13
#define INV_S (1.0f / 33554432.0f)   // 2^-25
#define TILE_F16 4096                // 128*32 f16 per tile
#define SLAB_F16 (16 * TILE_F16)     // 16 k-tiles per slab

typedef _Float16 f16;
typedef _Float16 f16x8 __attribute__((ext_vector_type(8)));
typedef float    f32x4 __attribute__((ext_vector_type(4)));

#define GLOAD_LDS16(g, l)                                                      \
  __builtin_amdgcn_global_load_lds(                                            \
      (const __attribute__((address_space(1))) void*)(g),                      \
      (__attribute__((address_space(3))) void*)(l), 16, 0, 0)

// -------- fused pre-pass: blocks 0..511 = W prep; 512.. = A split --------
// Tiled layout: plane[slab][kt][row][chunk p][8], p = c ^ ((row>>1)&3).
__global__ __launch_bounds__(256) void prep(
    const float* __restrict__ W, float* __restrict__ Wt,
    f16* __restrict__ WtH, f16* __restrict__ WtL, unsigned* __restrict__ cnt,
    const float* __restrict__ A, f16* __restrict__ AH, f16* __restrict__ AL,
    int M, int nAblocks)
{
    const int b = blockIdx.x;
    if (b < NUMD) {
        const int n = b;
        if (n == 0 && threadIdx.x == 0) *cnt = 0;
        const int slab = n >> 7, rn = n & 127;
        const int srow = (rn >> 1) & 3;
        for (int k = threadIdx.x; k < NUMD; k += 256) {
            float v = W[(size_t)k * NUMD + n];
            if (k == n) v = 0.0f;
            Wt[(size_t)n * NUMD + k] = v;      // unscaled fp32 for fixup
            const float vs = v * SW;
            f16 h  = (f16)vs;
            f16 lo = (f16)(vs - (float)h);     // UNSCALED residual
            const int kt = k >> 5, kk = k & 31, c = kk >> 3, e = kk & 7;
            const int p = c ^ srow;
            const size_t off = (size_t)slab * SLAB_F16 + (size_t)kt * TILE_F16
                             + rn * 32 + p * 8 + e;
            WtH[off] = h; WtL[off] = lo;
        }
    } else {
        const long total = (long)M * 64;       // 8-k chunks
        for (long i = (long)(b - NUMD) * 256 + threadIdx.x; i < total;
             i += (long)nAblocks * 256) {
            const int m = (int)(i >> 6), ch = (int)(i & 63);
            const int kt = ch >> 2, c = ch & 3;
            const int slab = m >> 7, rm = m & 127;
            const int p = c ^ ((rm >> 1) & 3);
            const float* src = A + (size_t)m * NUMD + (ch << 3);
            float4 a0 = *(const float4*)src;
            float4 a1 = *(const float4*)(src + 4);
            const float av[8] = {a0.x, a0.y, a0.z, a0.w, a1.x, a1.y, a1.z, a1.w};
            f16x8 h, lo;
#pragma unroll
            for (int e = 0; e < 8; ++e) {
                const float as = av[e] * SA;
                f16 hv = (f16)as;
                h[e]  = hv;
                lo[e] = (f16)(as - (float)hv); // UNSCALED residual
            }
            const size_t off = (size_t)slab * SLAB_F16 + (size_t)kt * TILE_F16
                             + rm * 32 + p * 8;
            *(f16x8*)(AH + off) = h;
            *(f16x8*)(AL + off) = lo;
        }
    }
}

// ---------------- main GEMM (scaled f16 split MFMA, single acc) ----------------
__global__ __launch_bounds__(256, 2) void li_mfma(
    const float* __restrict__ A,    // [M,512] fp32 (epilogue gate input)
    const f16* __restrict__ AH, const f16* __restrict__ AL,   // tiled
    const f16* __restrict__ WtH, const f16* __restrict__ WtL, // tiled
    const float* __restrict__ bias,
    float* __restrict__ out,
    unsigned* __restrict__ cnt, unsigned* __restrict__ list,
    int M, int cpx)
{
    // [2 bufs][4 planes][128 rows][32 k] f16 = 64 KiB -> 2 blocks/CU
    __shared__ __align__(16) f16 lds[2][4][128][32];
    __shared__ unsigned lcnt, lbase;

    const int tid = threadIdx.x;
    const int l   = tid & 63;
    const int wv  = tid >> 6;     // wave 0..3
    const int wr  = wv >> 1;      // wave row 0..1
    const int wc  = wv & 1;       // wave col 0..1
    const int lG  = l >> 4;       // k-chunk group 0..3
    const int lM  = l & 15;       // frag row/col

    int w = blockIdx.x;
    if (cpx) { const int xcd = w & 7, c = w >> 3; w = xcd * cpx + c; }
    const int m0  = (w >> 2) * 128;
    const int n0b = (w & 3) * 128;

    // DMA sources: tiled planes, fully contiguous 1KB per instruction.
    const size_t aOff = ((size_t)(m0 >> 7) * SLAB_F16) * 2 + wv * 2048 + l * 16;
    const size_t bOff = ((size_t)(n0b >> 7) * SLAB_F16) * 2 + wv * 2048 + l * 16;
    const char* pAH = (const char*)AH;
    const char* pAL = (const char*)AL;
    const char* pBH = (const char*)WtH;
    const char* pBL = (const char*)WtL;

#define STAGE(nb, ktb) do {                                                    \
    GLOAD_LDS16(pAH + aOff + (ktb),        &lds[nb][0][wv * 32][0]);           \
    GLOAD_LDS16(pAH + aOff + (ktb) + 1024, &lds[nb][0][wv * 32 + 16][0]);      \
    GLOAD_LDS16(pAL + aOff + (ktb),        &lds[nb][1][wv * 32][0]);           \
    GLOAD_LDS16(pAL + aOff + (ktb) + 1024, &lds[nb][1][wv * 32 + 16][0]);      \
    GLOAD_LDS16(pBH + bOff + (ktb),        &lds[nb][2][wv * 32][0]);           \
    GLOAD_LDS16(pBH + bOff + (ktb) + 1024, &lds[nb][2][wv * 32 + 16][0]);      \
    GLOAD_LDS16(pBL + bOff + (ktb),        &lds[nb][3][wv * 32][0]);           \
    GLOAD_LDS16(pBL + bOff + (ktb) + 1024, &lds[nb][3][wv * 32 + 16][0]);      \
  } while (0)

    // LDS read offsets: physical chunk lG ^ s(row) holds logical chunk lG.
    int aRd[4], bRd[4];
#pragma unroll
    for (int f = 0; f < 4; ++f) {
        const int mr = wr * 64 + f * 16 + lM;
        aRd[f] = mr * 64 + ((lG ^ ((mr >> 1) & 3)) << 4);
        const int nr = wc * 64 + f * 16 + lM;
        bRd[f] = nr * 64 + ((lG ^ ((nr >> 1) & 3)) << 4);
    }

    f32x4 acc[4][4];
#pragma unroll
    for (int i = 0; i < 4; ++i)
#pragma unroll
        for (int j = 0; j < 4; ++j) acc[i][j] = f32x4{0.f, 0.f, 0.f, 0.f};

    STAGE(0, 0);

    const int NT = NUMD / 32;   // 16
    for (int kt = 0; kt < NT; ++kt) {
        const int cur = kt & 1;
        __syncthreads();                       // drains tile-kt DMAs
        if (kt + 1 < NT) STAGE(cur ^ 1, (size_t)(kt + 1) * 8192);

        const char* PAH = (const char*)&lds[cur][0][0][0];
        const char* PAL = (const char*)&lds[cur][1][0][0];
        const char* PBH = (const char*)&lds[cur][2][0][0];
        const char* PBL = (const char*)&lds[cur][3][0][0];

        f16x8 bh[4], bl[4];
#pragma unroll
        for (int fj = 0; fj < 4; ++fj) {
            bh[fj] = *(const f16x8*)(PBH + bRd[fj]);
            bl[fj] = *(const f16x8*)(PBL + bRd[fj]);
        }
        __builtin_amdgcn_s_setprio(1);
#pragma unroll
        for (int fi = 0; fi < 4; ++fi) {
            const f16x8 ah = *(const f16x8*)(PAH + aRd[fi]);
            const f16x8 al = *(const f16x8*)(PAL + aRd[fi]);
#pragma unroll
            for (int fj = 0; fj < 4; ++fj) {
                acc[fi][fj] = __builtin_amdgcn_mfma_f32_16x16x32_f16(ah, bh[fj], acc[fi][fj], 0, 0, 0);
                acc[fi][fj] = __builtin_amdgcn_mfma_f32_16x16x32_f16(ah, bl[fj], acc[fi][fj], 0, 0, 0);
                acc[fi][fj] = __builtin_amdgcn_mfma_f32_16x16x32_f16(al, bh[fj], acc[fi][fj], 0, 0, 0);
            }
        }
        __builtin_amdgcn_s_setprio(0);
    }

    // ---- staging LDS dead; reuse as per-block fix-list buffer
    __syncthreads();
    unsigned* lbuf = (unsigned*)&lds[0][0][0][0];
    if (tid == 0) lcnt = 0;
    __syncthreads();

    // epilogue: C/D layout col=lane&15, row=(lane>>4)*4+reg (m89-verified)
#pragma unroll
    for (int fj = 0; fj < 4; ++fj) {
        const int n = n0b + wc * 64 + fj * 16 + lM;
        const float bvj = bias[n];
#pragma unroll
        for (int fi = 0; fi < 4; ++fi) {
            const int mb = m0 + wr * 64 + fi * 16 + lG * 4;
#pragma unroll
            for (int r = 0; r < 4; ++r) {
                const size_t idx = (size_t)(mb + r) * NUMD + n;
                const float inh = acc[fi][fj][r] * INV_S + bvj;
                const float x = A[idx];
                out[idx] = (inh > 0.0f) ? x : 0.0f;
                if (__builtin_fabsf(inh) <= EPS) {
                    unsigned p = atomicAdd(&lcnt, 1u);   // LDS atomic
                    if (p < LCAP) lbuf[p] = (unsigned)idx;
                }
            }
        }
    }

    __syncthreads();
    if (tid == 0) {
        unsigned nf = lcnt; if (nf > LCAP) nf = LCAP;
        lbase = atomicAdd(cnt, nf);
    }
    __syncthreads();
    {
        unsigned nf = lcnt; if (nf > LCAP) nf = LCAP;
        for (unsigned i = tid; i < nf; i += 256) {
            const unsigned p = lbase + i;
            if (p < FIXCAP) list[p] = lbuf[i];
        }
    }
#undef STAGE
}

// ------- fixup: exact fp32 recompute, BIT-IDENTICAL order to the proven v4 path -------
__global__ __launch_bounds__(256) void fixup(
    const float* __restrict__ A, const float* __restrict__ Wt,
    const float* __restrict__ bias, float* __restrict__ out,
    const unsigned* __restrict__ cnt, const unsigned* __restrict__ list,
    unsigned total)
{
    unsigned nfix = *cnt;
    if (nfix > FIXCAP) nfix = FIXCAP;
    for (unsigned e = blockIdx.x * blockDim.x + threadIdx.x; e < nfix;
         e += gridDim.x * blockDim.x) {
        const unsigned code = list[e];
        if (code >= total) continue;
        const int n = (int)(code & 511);
        const float* ar = A  + (size_t)(code >> 9) * NUMD;
        const float* wr = Wt + (size_t)n * NUMD;
        float s = 0.0f;
#pragma unroll 8
        for (int k = 0; k < NUMD; ++k)
            s = fmaf(ar[k], wr[k], s);         // strict k-ascending chain
        const float inh = s + bias[n];
        out[code] = (inh > 0.0f) ? A[code] : 0.0f;
    }
}

// ---------------- fallback: v4 exact fp32 path (proven 205us) ----------------
#define BM 128
#define BN 256
#define BK 16
#define TM 8
#define TN 16
#define NTF (NUMD / BK)

__global__ __launch_bounds__(256) void zero_diag_kernel(
    const float* __restrict__ W, float* __restrict__ Wz)
{
    const int f = (int)(blockIdx.x * blockDim.x + threadIdx.x) * 4;
    const int row = f >> 9, col0 = f & 511;
    float4 v = *(const float4*)(W + f);
    if (row == col0 + 0) v.x = 0.0f;
    if (row == col0 + 1) v.y = 0.0f;
    if (row == col0 + 2) v.z = 0.0f;
    if (row == col0 + 3) v.w = 0.0f;
    *(float4*)(Wz + f) = v;
}

template<bool ZDIAG>
__global__ __launch_bounds__(256, 1) void li_gemm_fp32(
    const float* __restrict__ A, const float* __restrict__ Wm,
    const float* __restrict__ bias, float* __restrict__ out, int M)
{
    __shared__ __align__(16) float As[2][BM][BK];
    __shared__ __align__(16) float Bs[2][BK][BN];
    const int tid = threadIdx.x, lane = tid & 63, wv = tid >> 6;
    const int tc = tid & 15, tr = tid >> 4;
    const int m0 = blockIdx.x * BM, n0 = blockIdx.y * BN;
    const int am0 = wv * 32 + (lane >> 2), am1 = am0 + 16;
    const int q0 = ((lane & 3) ^ ((am0 >> 3) & 3)) << 2;
    const int q1 = ((lane & 3) ^ ((am1 >> 3) & 3)) << 2;
    const float* aSrc0 = A + (size_t)(m0 + am0) * NUMD + q0;
    const float* aSrc1 = A + (size_t)(m0 + am1) * NUMD + q1;
    const float* wSrc = Wm + (size_t)(wv * 4) * NUMD + n0 + lane * 4;
    float acc[TM][TN];
#pragma unroll
    for (int i = 0; i < TM; ++i)
#pragma unroll
        for (int j = 0; j < TN; ++j) acc[i][j] = 0.0f;
    GLOAD_LDS16(aSrc0, &As[0][wv * 32][0]);
    GLOAD_LDS16(aSrc1, &As[0][wv * 32 + 16][0]);
#pragma unroll
    for (int r = 0; r < 4; ++r)
        GLOAD_LDS16(wSrc + (size_t)r * NUMD, &Bs[0][wv * 4 + r][0]);
    aSrc0 += BK; aSrc1 += BK; wSrc += (size_t)BK * NUMD;
    for (int kt = 0; kt < NTF; ++kt) {
        const int cur = kt & 1;
        __syncthreads();
        if (kt + 1 < NTF) {
            const int nb = cur ^ 1;
            GLOAD_LDS16(aSrc0, &As[nb][wv * 32][0]);
            GLOAD_LDS16(aSrc1, &As[nb][wv * 32 + 16][0]);
#pragma unroll
            for (int r = 0; r < 4; ++r)
                GLOAD_LDS16(wSrc + (size_t)r * NUMD, &Bs[nb][wv * 4 + r][0]);
            aSrc0 += BK; aSrc1 += BK; wSrc += (size_t)BK * NUMD;
        }
        if (ZDIAG) {
            const int kk = kt * BK;
            if (tid < BK) {
                const int col = kk + tid - n0;
                if (col >= 0 && col < BN) Bs[cur][tid][col] = 0.0f;
            }
            __syncthreads();
        }
#pragma unroll
        for (int g = 0; g < 4; ++g) {
            float4 af[TM];
#pragma unroll
            for (int i = 0; i < TM; ++i) {
                const int m = tr * TM + i;
                af[i] = *(const float4*)&As[cur][m][(g ^ ((m >> 3) & 3)) << 2];
            }
#pragma unroll
            for (int dk = 0; dk < 4; ++dk) {
                float b[TN];
#pragma unroll
                for (int c = 0; c < 4; ++c) {
                    float4 b4 = *(const float4*)&Bs[cur][g * 4 + dk][tc * 4 + 64 * c];
                    b[4*c+0] = b4.x; b[4*c+1] = b4.y; b[4*c+2] = b4.z; b[4*c+3] = b4.w;
                }
#pragma unroll
                for (int i = 0; i < TM; ++i) {
                    const float a = ((const float*)&af[i])[dk];
#pragma unroll
                    for (int j = 0; j < TN; ++j) acc[i][j] = fmaf(a, b[j], acc[i][j]);
                }
            }
        }
    }
    float bv[TN];
#pragma unroll
    for (int c = 0; c < 4; ++c) {
        float4 b4 = *(const float4*)(bias + n0 + tc * 4 + 64 * c);
        bv[4*c+0] = b4.x; bv[4*c+1] = b4.y; bv[4*c+2] = b4.z; bv[4*c+3] = b4.w;
    }
#pragma unroll
    for (int i = 0; i < TM; ++i) {
        const int gm = m0 + tr * TM + i;
        const float* inrow = A + (size_t)gm * NUMD + n0 + tc * 4;
        float* orow = out + (size_t)gm * NUMD + n0 + tc * 4;
#pragma unroll
        for (int c = 0; c < 4; ++c) {
            float4 x = *(const float4*)(inrow + 64 * c);
            float4 o;
            o.x = (acc[i][4*c+0] + bv[4*c+0] > 0.0f) ? x.x : 0.0f;
            o.y = (acc[i][4*c+1] + bv[4*c+1] > 0.0f) ? x.y : 0.0f;
            o.z = (acc[i][4*c+2] + bv[4*c+2] > 0.0f) ? x.z : 0.0f;
            o.w = (acc[i][4*c+3] + bv[4*c+3] > 0.0f) ? x.w : 0.0f;
            *(float4*)(orow + 64 * c) = o;
        }
    }
}

extern "C" void kernel_launch(void* const* d_in, const int* in_sizes, int n_in,
                              void* d_out, int out_size, void* d_ws, size_t ws_size,
                              hipStream_t stream) {
    const float* A    = (const float*)d_in[0];
    const float* W    = (const float*)d_in[1];
    const float* bias = (const float*)d_in[2];
    float* out        = (float*)d_out;
    const int M = in_sizes[0] / NUMD;           // 32768

    const size_t szA  = (size_t)M * NUMD * 2;   // one f16 copy of A
    const size_t need = (2u << 20) + 2 * szA + 1024 + 4 * (size_t)FIXCAP;

    if (ws_size >= need) {
        char* wsb = (char*)d_ws;
        float*    Wt   = (float*)wsb;                              // 1 MiB
        f16*      WtH  = (f16*)(wsb + (1u << 20));                 // 512 KiB tiled
        f16*      WtL  = (f16*)(wsb + (1u << 20) + (512u << 10));  // 512 KiB tiled
        f16*      AH   = (f16*)(wsb + (2u << 20));                 // tiled
        f16*      AL   = (f16*)(wsb + (2u << 20) + szA);           // tiled
        unsigned* cnt  = (unsigned*)(wsb + (2u << 20) + 2 * szA);
        unsigned* list = cnt + 256;

        const int nAblocks = 4096;
        prep<<<dim3(NUMD + nAblocks), 256, 0, stream>>>(
            W, Wt, WtH, WtL, cnt, A, AH, AL, M, nAblocks);
        const int nwg = (M / 128) * (NUMD / 128);
        const int cpx = (nwg % 8 == 0) ? (nwg / 8) : 0;
        li_mfma<<<dim3(nwg), 256, 0, stream>>>(A, AH, AL, WtH, WtL, bias, out,
                                               cnt, list, M, cpx);
        fixup<<<dim3(256), 256, 0, stream>>>(A, Wt, bias, out, cnt, list,
                                             (unsigned)((size_t)M * NUMD));
    } else {
        dim3 grid(M / BM, NUMD / BN);
        const size_t wbytes = (size_t)NUMD * NUMD * sizeof(float);
        if (ws_size >= wbytes) {
            float* Wz = (float*)d_ws;
            zero_diag_kernel<<<dim3(NUMD * NUMD / (4 * 256)), 256, 0, stream>>>(W, Wz);
            li_gemm_fp32<false><<<grid, 256, 0, stream>>>(A, Wz, bias, out, M);
        } else {
            li_gemm_fp32<true><<<grid, 256, 0, stream>>>(A, W, bias, out, M);
        }
    }
}

// Round 12
// 230.783 us; speedup vs baseline: 2.2332x; 1.0473x over previous
//
#include <hip/hip_runtime.h>
#include <stdint.h>

// LateralInhibition: out = inputs * ((inputs @ w1 + b) > 0), w1 = w with zero diag.
// v12 = v11 (PASSED, 242us; li_mfma 95us) with the A-split prep FUSED into the
//       GEMM. Overhead analysis: prep+fixup+gaps were a constant ~145us across
//       v9/v10/v11 while li_mfma shrank 161->95; prep's A-pass moves 128MB
//       (64 R + 64 W) that the GEMM can absorb: A planes are now reg-staged
//       in-kernel from fp32 A (coalesced loads issued right after the barrier,
//       convert ~60 VALU/thread/tile hides under MFMA - separate pipes),
//       ds_write_b128 to the same XOR-swizzled offsets. GEMM A-bytes unchanged
//       (4B/elem either way). prep is now W-only (1MB, ~5us).
// Numerics (v11-proven, absmax 0.0, BIT-identical op order kept):
//   A*2^12, W*2^13 pre-scale (kills f16 denormal flush), single accumulator
//   at scale 2^25 (ah*bh + ah*bl + al*bh; lo*lo omitted <=7.4e-5), /2^25
//   exact epilogue; |inh|<=1e-3 flagged via LDS-aggregated list; fixup
//   recomputes flagged elements with EXACT v4 fp32 k-ascending fmaf order.
// Structure: 128x128 tile, 4 waves 2x2, B via global_load_lds from pre-tiled
// workspace (1KB contiguous per DMA), A via reg-staging, 2-buffer
// __syncthreads schedule, XCD-chunked block swizzle, 2 blocks/CU.

#define NUMD 512
#define EPS 1e-3f
#define FIXCAP (1u << 20)
#define LCAP 2048u
#define SA 4096.0f                   // 2^12
#define SW 8192.0f                   // 2^13
#define INV_S (1.0f / 33554432.0f)   // 2^-25
#define TILE_F16 4096                // 128*32 f16 per tile
#define SLAB_F16 (16 * TILE_F16)     // 16 k-tiles per slab

typedef _Float16 f16;
typedef _Float16 f16x8 __attribute__((ext_vector_type(8)));
typedef float    f32x4 __attribute__((ext_vector_type(4)));

#define GLOAD_LDS16(g, l)                                                      \
  __builtin_amdgcn_global_load_lds(                                            \
      (const __attribute__((address_space(1))) void*)(g),                      \
      (__attribute__((address_space(3))) void*)(l), 16, 0, 0)

// -------- pre-pass (W only): transpose + diag-zero + scaled f16 split, tiled --------
// Tiled layout: plane[slab][kt][row][chunk p][8], p = c ^ ((row>>1)&3).
__global__ __launch_bounds__(256) void prep(
    const float* __restrict__ W, float* __restrict__ Wt,
    f16* __restrict__ WtH, f16* __restrict__ WtL, unsigned* __restrict__ cnt)
{
    const int n = blockIdx.x;
    if (n == 0 && threadIdx.x == 0) *cnt = 0;
    const int slab = n >> 7, rn = n & 127;
    const int srow = (rn >> 1) & 3;
    for (int k = threadIdx.x; k < NUMD; k += 256) {
        float v = W[(size_t)k * NUMD + n];
        if (k == n) v = 0.0f;
        Wt[(size_t)n * NUMD + k] = v;          // unscaled fp32 for fixup
        const float vs = v * SW;
        f16 h  = (f16)vs;
        f16 lo = (f16)(vs - (float)h);         // unscaled residual
        const int kt = k >> 5, kk = k & 31, c = kk >> 3, e = kk & 7;
        const int p = c ^ srow;
        const size_t off = (size_t)slab * SLAB_F16 + (size_t)kt * TILE_F16
                         + rn * 32 + p * 8 + e;
        WtH[off] = h; WtL[off] = lo;
    }
}

// ---------------- main GEMM (fused A-split, scaled f16 MFMA) ----------------
__global__ __launch_bounds__(256, 2) void li_mfma(
    const float* __restrict__ A,    // [M,512] fp32
    const f16* __restrict__ WtH, const f16* __restrict__ WtL, // tiled
    const float* __restrict__ bias,
    float* __restrict__ out,
    unsigned* __restrict__ cnt, unsigned* __restrict__ list,
    int M, int cpx)
{
    // [2 bufs][4 planes: AH AL BH BL][128 rows][32 k] f16 = 64 KiB
    __shared__ __align__(16) f16 lds[2][4][128][32];
    __shared__ unsigned lcnt, lbase;

    const int tid = threadIdx.x;
    const int l   = tid & 63;
    const int wv  = tid >> 6;     // wave 0..3
    const int wr  = wv >> 1;      // wave row 0..1
    const int wc  = wv & 1;       // wave col 0..1
    const int lG  = l >> 4;       // k-chunk group 0..3
    const int lM  = l & 15;       // frag row/col

    int w = blockIdx.x;
    if (cpx) { const int xcd = w & 7, c = w >> 3; w = xcd * cpx + c; }
    const int m0  = (w >> 2) * 128;
    const int n0b = (w & 3) * 128;

    // ---- B DMA source (tiled planes, contiguous 1KB per instruction)
    const size_t bOff = ((size_t)(n0b >> 7) * SLAB_F16) * 2 + wv * 2048 + l * 16;
    const char* pBH = (const char*)WtH;
    const char* pBL = (const char*)WtL;

#define STAGE_B(nb, ktb) do {                                                  \
    GLOAD_LDS16(pBH + bOff + (ktb),        &lds[nb][2][wv * 32][0]);           \
    GLOAD_LDS16(pBH + bOff + (ktb) + 1024, &lds[nb][2][wv * 32 + 16][0]);      \
    GLOAD_LDS16(pBL + bOff + (ktb),        &lds[nb][3][wv * 32][0]);           \
    GLOAD_LDS16(pBL + bOff + (ktb) + 1024, &lds[nb][3][wv * 32 + 16][0]);      \
  } while (0)

    // ---- A staging (reg path): tasks i in {tid, tid+256}; row=i>>2, c=i&3.
    // Consecutive tids read consecutive 32B of A -> fully coalesced.
    const int r0 = tid >> 2, ca = tid & 3;
    const int r1 = r0 + 64;
    const float* aBase0 = A + (size_t)(m0 + r0) * NUMD + ca * 8;
    const float* aBase1 = A + (size_t)(m0 + r1) * NUMD + ca * 8;
    // plane-local ds_write byte offsets (same XOR as the read side)
    const int wo0 = r0 * 64 + ((ca ^ ((r0 >> 1) & 3)) << 4);
    const int wo1 = r1 * 64 + ((ca ^ ((r1 >> 1) & 3)) << 4);

    float4 av00, av01, av10, av11;             // in-flight A fp32 (2 chunks)

#define ALOAD(kt) do {                                                         \
    const float* s0 = aBase0 + (size_t)(kt) * 32;                              \
    const float* s1 = aBase1 + (size_t)(kt) * 32;                              \
    av00 = *(const float4*)s0; av01 = *(const float4*)(s0 + 4);                \
    av10 = *(const float4*)s1; av11 = *(const float4*)(s1 + 4);                \
  } while (0)

#define ACONV(nb) do {                                                         \
    const float a0[8] = {av00.x, av00.y, av00.z, av00.w,                       \
                         av01.x, av01.y, av01.z, av01.w};                      \
    const float a1[8] = {av10.x, av10.y, av10.z, av10.w,                       \
                         av11.x, av11.y, av11.z, av11.w};                      \
    f16x8 h0, lo0, h1, lo1;                                                    \
    _Pragma("unroll")                                                          \
    for (int e = 0; e < 8; ++e) {                                              \
        float as0 = a0[e] * SA; f16 hv0 = (f16)as0;                            \
        h0[e] = hv0; lo0[e] = (f16)(as0 - (float)hv0);                         \
        float as1 = a1[e] * SA; f16 hv1 = (f16)as1;                            \
        h1[e] = hv1; lo1[e] = (f16)(as1 - (float)hv1);                         \
    }                                                                          \
    *(f16x8*)((char*)&lds[nb][0][0][0] + wo0) = h0;                            \
    *(f16x8*)((char*)&lds[nb][1][0][0] + wo0) = lo0;                           \
    *(f16x8*)((char*)&lds[nb][0][0][0] + wo1) = h1;                            \
    *(f16x8*)((char*)&lds[nb][1][0][0] + wo1) = lo1;                           \
  } while (0)

    // LDS read offsets: physical chunk lG ^ s(row) holds logical chunk lG.
    int aRd[4], bRd[4];
#pragma unroll
    for (int f = 0; f < 4; ++f) {
        const int mr = wr * 64 + f * 16 + lM;
        aRd[f] = mr * 64 + ((lG ^ ((mr >> 1) & 3)) << 4);
        const int nr = wc * 64 + f * 16 + lM;
        bRd[f] = nr * 64 + ((lG ^ ((nr >> 1) & 3)) << 4);
    }

    f32x4 acc[4][4];
#pragma unroll
    for (int i = 0; i < 4; ++i)
#pragma unroll
        for (int j = 0; j < 4; ++j) acc[i][j] = f32x4{0.f, 0.f, 0.f, 0.f};

    // prologue: tile 0
    ALOAD(0);
    STAGE_B(0, 0);
    ACONV(0);

    const int NT = NUMD / 32;   // 16
    for (int kt = 0; kt < NT; ++kt) {
        const int cur = kt & 1;
        __syncthreads();        // publishes tile kt (DMA vmcnt + ds_writes + barrier)

        // issue next tile's loads EARLY so latency hides under this compute
        if (kt + 1 < NT) {
            STAGE_B(cur ^ 1, (size_t)(kt + 1) * 8192);
            ALOAD(kt + 1);
        }

        const char* PAH = (const char*)&lds[cur][0][0][0];
        const char* PAL = (const char*)&lds[cur][1][0][0];
        const char* PBH = (const char*)&lds[cur][2][0][0];
        const char* PBL = (const char*)&lds[cur][3][0][0];

        f16x8 bh[4], bl[4];
#pragma unroll
        for (int fj = 0; fj < 4; ++fj) {
            bh[fj] = *(const f16x8*)(PBH + bRd[fj]);
            bl[fj] = *(const f16x8*)(PBL + bRd[fj]);
        }
        __builtin_amdgcn_s_setprio(1);
#pragma unroll
        for (int fi = 0; fi < 4; ++fi) {
            const f16x8 ah = *(const f16x8*)(PAH + aRd[fi]);
            const f16x8 al = *(const f16x8*)(PAL + aRd[fi]);
#pragma unroll
            for (int fj = 0; fj < 4; ++fj) {
                acc[fi][fj] = __builtin_amdgcn_mfma_f32_16x16x32_f16(ah, bh[fj], acc[fi][fj], 0, 0, 0);
                acc[fi][fj] = __builtin_amdgcn_mfma_f32_16x16x32_f16(ah, bl[fj], acc[fi][fj], 0, 0, 0);
                acc[fi][fj] = __builtin_amdgcn_mfma_f32_16x16x32_f16(al, bh[fj], acc[fi][fj], 0, 0, 0);
            }
        }
        __builtin_amdgcn_s_setprio(0);

        // convert + write next tile's A planes into buf^1 (safe: all waves
        // finished reading buf^1 before the barrier at the top of THIS kt)
        if (kt + 1 < NT) ACONV(cur ^ 1);
    }

    // ---- staging LDS dead; reuse as per-block fix-list buffer
    __syncthreads();
    unsigned* lbuf = (unsigned*)&lds[0][0][0][0];
    if (tid == 0) lcnt = 0;
    __syncthreads();

    // epilogue: C/D layout col=lane&15, row=(lane>>4)*4+reg (m89-verified)
#pragma unroll
    for (int fj = 0; fj < 4; ++fj) {
        const int n = n0b + wc * 64 + fj * 16 + lM;
        const float bvj = bias[n];
#pragma unroll
        for (int fi = 0; fi < 4; ++fi) {
            const int mb = m0 + wr * 64 + fi * 16 + lG * 4;
#pragma unroll
            for (int r = 0; r < 4; ++r) {
                const size_t idx = (size_t)(mb + r) * NUMD + n;
                const float inh = acc[fi][fj][r] * INV_S + bvj;
                const float x = A[idx];
                out[idx] = (inh > 0.0f) ? x : 0.0f;
                if (__builtin_fabsf(inh) <= EPS) {
                    unsigned p = atomicAdd(&lcnt, 1u);   // LDS atomic
                    if (p < LCAP) lbuf[p] = (unsigned)idx;
                }
            }
        }
    }

    __syncthreads();
    if (tid == 0) {
        unsigned nf = lcnt; if (nf > LCAP) nf = LCAP;
        lbase = atomicAdd(cnt, nf);
    }
    __syncthreads();
    {
        unsigned nf = lcnt; if (nf > LCAP) nf = LCAP;
        for (unsigned i = tid; i < nf; i += 256) {
            const unsigned p = lbase + i;
            if (p < FIXCAP) list[p] = lbuf[i];
        }
    }
#undef STAGE_B
#undef ALOAD
#undef ACONV
}

// ------- fixup: exact fp32 recompute, BIT-IDENTICAL order to the proven v4 path -------
__global__ __launch_bounds__(256) void fixup(
    const float* __restrict__ A, const float* __restrict__ Wt,
    const float* __restrict__ bias, float* __restrict__ out,
    const unsigned* __restrict__ cnt, const unsigned* __restrict__ list,
    unsigned total)
{
    unsigned nfix = *cnt;
    if (nfix > FIXCAP) nfix = FIXCAP;
    for (unsigned e = blockIdx.x * blockDim.x + threadIdx.x; e < nfix;
         e += gridDim.x * blockDim.x) {
        const unsigned code = list[e];
        if (code >= total) continue;
        const int n = (int)(code & 511);
        const float* ar = A  + (size_t)(code >> 9) * NUMD;
        const float* wr = Wt + (size_t)n * NUMD;
        float s = 0.0f;
#pragma unroll 8
        for (int k = 0; k < NUMD; ++k)
            s = fmaf(ar[k], wr[k], s);         // strict k-ascending chain
        const float inh = s + bias[n];
        out[code] = (inh > 0.0f) ? A[code] : 0.0f;
    }
}

// ---------------- fallback: v4 exact fp32 path (proven 205us) ----------------
#define BM 128
#define BN 256
#define BK 16
#define TM 8
#define TN 16
#define NTF (NUMD / BK)

__global__ __launch_bounds__(256) void zero_diag_kernel(
    const float* __restrict__ W, float* __restrict__ Wz)
{
    const int f = (int)(blockIdx.x * blockDim.x + threadIdx.x) * 4;
    const int row = f >> 9, col0 = f & 511;
    float4 v = *(const float4*)(W + f);
    if (row == col0 + 0) v.x = 0.0f;
    if (row == col0 + 1) v.y = 0.0f;
    if (row == col0 + 2) v.z = 0.0f;
    if (row == col0 + 3) v.w = 0.0f;
    *(float4*)(Wz + f) = v;
}

template<bool ZDIAG>
__global__ __launch_bounds__(256, 1) void li_gemm_fp32(
    const float* __restrict__ A, const float* __restrict__ Wm,
    const float* __restrict__ bias, float* __restrict__ out, int M)
{
    __shared__ __align__(16) float As[2][BM][BK];
    __shared__ __align__(16) float Bs[2][BK][BN];
    const int tid = threadIdx.x, lane = tid & 63, wv = tid >> 6;
    const int tc = tid & 15, tr = tid >> 4;
    const int m0 = blockIdx.x * BM, n0 = blockIdx.y * BN;
    const int am0 = wv * 32 + (lane >> 2), am1 = am0 + 16;
    const int q0 = ((lane & 3) ^ ((am0 >> 3) & 3)) << 2;
    const int q1 = ((lane & 3) ^ ((am1 >> 3) & 3)) << 2;
    const float* aSrc0 = A + (size_t)(m0 + am0) * NUMD + q0;
    const float* aSrc1 = A + (size_t)(m0 + am1) * NUMD + q1;
    const float* wSrc = Wm + (size_t)(wv * 4) * NUMD + n0 + lane * 4;
    float acc[TM][TN];
#pragma unroll
    for (int i = 0; i < TM; ++i)
#pragma unroll
        for (int j = 0; j < TN; ++j) acc[i][j] = 0.0f;
    GLOAD_LDS16(aSrc0, &As[0][wv * 32][0]);
    GLOAD_LDS16(aSrc1, &As[0][wv * 32 + 16][0]);
#pragma unroll
    for (int r = 0; r < 4; ++r)
        GLOAD_LDS16(wSrc + (size_t)r * NUMD, &Bs[0][wv * 4 + r][0]);
    aSrc0 += BK; aSrc1 += BK; wSrc += (size_t)BK * NUMD;
    for (int kt = 0; kt < NTF; ++kt) {
        const int cur = kt & 1;
        __syncthreads();
        if (kt + 1 < NTF) {
            const int nb = cur ^ 1;
            GLOAD_LDS16(aSrc0, &As[nb][wv * 32][0]);
            GLOAD_LDS16(aSrc1, &As[nb][wv * 32 + 16][0]);
#pragma unroll
            for (int r = 0; r < 4; ++r)
                GLOAD_LDS16(wSrc + (size_t)r * NUMD, &Bs[nb][wv * 4 + r][0]);
            aSrc0 += BK; aSrc1 += BK; wSrc += (size_t)BK * NUMD;
        }
        if (ZDIAG) {
            const int kk = kt * BK;
            if (tid < BK) {
                const int col = kk + tid - n0;
                if (col >= 0 && col < BN) Bs[cur][tid][col] = 0.0f;
            }
            __syncthreads();
        }
#pragma unroll
        for (int g = 0; g < 4; ++g) {
            float4 af[TM];
#pragma unroll
            for (int i = 0; i < TM; ++i) {
                const int m = tr * TM + i;
                af[i] = *(const float4*)&As[cur][m][(g ^ ((m >> 3) & 3)) << 2];
            }
#pragma unroll
            for (int dk = 0; dk < 4; ++dk) {
                float b[TN];
#pragma unroll
                for (int c = 0; c < 4; ++c) {
                    float4 b4 = *(const float4*)&Bs[cur][g * 4 + dk][tc * 4 + 64 * c];
                    b[4*c+0] = b4.x; b[4*c+1] = b4.y; b[4*c+2] = b4.z; b[4*c+3] = b4.w;
                }
#pragma unroll
                for (int i = 0; i < TM; ++i) {
                    const float a = ((const float*)&af[i])[dk];
#pragma unroll
                    for (int j = 0; j < TN; ++j) acc[i][j] = fmaf(a, b[j], acc[i][j]);
                }
            }
        }
    }
    float bv[TN];
#pragma unroll
    for (int c = 0; c < 4; ++c) {
        float4 b4 = *(const float4*)(bias + n0 + tc * 4 + 64 * c);
        bv[4*c+0] = b4.x; bv[4*c+1] = b4.y; bv[4*c+2] = b4.z; bv[4*c+3] = b4.w;
    }
#pragma unroll
    for (int i = 0; i < TM; ++i) {
        const int gm = m0 + tr * TM + i;
        const float* inrow = A + (size_t)gm * NUMD + n0 + tc * 4;
        float* orow = out + (size_t)gm * NUMD + n0 + tc * 4;
#pragma unroll
        for (int c = 0; c < 4; ++c) {
            float4 x = *(const float4*)(inrow + 64 * c);
            float4 o;
            o.x = (acc[i][4*c+0] + bv[4*c+0] > 0.0f) ? x.x : 0.0f;
            o.y = (acc[i][4*c+1] + bv[4*c+1] > 0.0f) ? x.y : 0.0f;
            o.z = (acc[i][4*c+2] + bv[4*c+2] > 0.0f) ? x.z : 0.0f;
            o.w = (acc[i][4*c+3] + bv[4*c+3] > 0.0f) ? x.w : 0.0f;
            *(float4*)(orow + 64 * c) = o;
        }
    }
}

extern "C" void kernel_launch(void* const* d_in, const int* in_sizes, int n_in,
                              void* d_out, int out_size, void* d_ws, size_t ws_size,
                              hipStream_t stream) {
    const float* A    = (const float*)d_in[0];
    const float* W    = (const float*)d_in[1];
    const float* bias = (const float*)d_in[2];
    float* out        = (float*)d_out;
    const int M = in_sizes[0] / NUMD;           // 32768

    const size_t need = (2u << 20) + 1024 + 4 * (size_t)FIXCAP + 4096;

    if (ws_size >= need) {
        char* wsb = (char*)d_ws;
        float*    Wt   = (float*)wsb;                              // 1 MiB
        f16*      WtH  = (f16*)(wsb + (1u << 20));                 // 512 KiB tiled
        f16*      WtL  = (f16*)(wsb + (1u << 20) + (512u << 10));  // 512 KiB tiled
        unsigned* cnt  = (unsigned*)(wsb + (2u << 20));
        unsigned* list = cnt + 256;

        prep<<<dim3(NUMD), 256, 0, stream>>>(W, Wt, WtH, WtL, cnt);
        const int nwg = (M / 128) * (NUMD / 128);
        const int cpx = (nwg % 8 == 0) ? (nwg / 8) : 0;
        li_mfma<<<dim3(nwg), 256, 0, stream>>>(A, WtH, WtL, bias, out,
                                               cnt, list, M, cpx);
        fixup<<<dim3(256), 256, 0, stream>>>(A, Wt, bias, out, cnt, list,
                                             (unsigned)((size_t)M * NUMD));
    } else {
        dim3 grid(M / BM, NUMD / BN);
        const size_t wbytes = (size_t)NUMD * NUMD * sizeof(float);
        if (ws_size >= wbytes) {
            float* Wz = (float*)d_ws;
            zero_diag_kernel<<<dim3(NUMD * NUMD / (4 * 256)), 256, 0, stream>>>(W, Wz);
            li_gemm_fp32<false><<<grid, 256, 0, stream>>>(A, Wz, bias, out, M);
        } else {
            li_gemm_fp32<true><<<grid, 256, 0, stream>>>(A, W, bias, out, M);
        }
    }
}

// Round 13
// 203.577 us; speedup vs baseline: 2.5317x; 1.1336x over previous
//
#include <hip/hip_runtime.h>
#include <stdint.h>

// LateralInhibition: out = inputs * ((inputs @ w1 + b) > 0), w1 = w with zero diag.
// v13 = v12 (PASSED 231us; li_mfma 107us) with fixup FOLDED INTO the GEMM and a
//       vectorized epilogue.
//  - accounting across v9..v12: harness carries ~78us fixed overhead above the
//    dispatch sum (v1: 320 total vs 242 dispatch). Actionable remainder was the
//    fixup dispatch + gap (~30-45us) and li_mfma's scalar-store epilogue
//    (WRITE_SIZE 91MB vs 64MB out = partial-line amplification).
//  - fix 1 (inline fixup): flagged |inh|<=1e-3 elements -> per-block LDS list
//    (~29/block expected); after the bulk store the SAME block recomputes them
//    with the byte-identical v4 fp32 k-ascending fmaf chain (A row + Wt row)
//    and overwrites out. Global cnt/list + third kernel launch deleted.
//    Ordering safe: __syncthreads drains vmcnt(0) -> bulk stores complete
//    before fix stores to the same addresses.
//  - fix 2 (vector epilogue): acc -> cbuf[128][128] fp32 in LDS (aliases the
//    dead 64KB staging buffer exactly), then coalesced float4 reads of
//    cbuf/A/bias and float4 out stores (32 lanes = 512B segments).
//    inh = cbuf + bias is op-identical to v12 -> same gate bits -> absmax 0.0.
// Numerics (v11/v12-proven): A*2^12 (in-kernel split), W*2^13 (prep), single
// acc at 2^25 (ah*bh + ah*bl + al*bh), /2^25 exact.
// Structure: 128x128 tile, 4 waves 2x2, B via global_load_lds from pre-tiled
// ws (1KB contiguous per DMA), A reg-staged+converted in-kernel, 2-buffer
// __syncthreads schedule, XCD-chunked swizzle, 2 blocks/CU.

#define NUMD 512
#define EPS 1e-3f
#define FLCAP 512u                   // per-block fix-list capacity (mean ~29)
#define SA 4096.0f                   // 2^12
#define SW 8192.0f                   // 2^13
#define INV_S (1.0f / 33554432.0f)   // 2^-25
#define TILE_F16 4096                // 128*32 f16 per tile
#define SLAB_F16 (16 * TILE_F16)     // 16 k-tiles per slab

typedef _Float16 f16;
typedef _Float16 f16x8 __attribute__((ext_vector_type(8)));
typedef float    f32x4 __attribute__((ext_vector_type(4)));

#define GLOAD_LDS16(g, l)                                                      \
  __builtin_amdgcn_global_load_lds(                                            \
      (const __attribute__((address_space(1))) void*)(g),                      \
      (__attribute__((address_space(3))) void*)(l), 16, 0, 0)

// -------- pre-pass (W only): transpose + diag-zero + scaled f16 split, tiled --------
// Tiled layout: plane[slab][kt][row][chunk p][8], p = c ^ ((row>>1)&3).
__global__ __launch_bounds__(256) void prep(
    const float* __restrict__ W, float* __restrict__ Wt,
    f16* __restrict__ WtH, f16* __restrict__ WtL)
{
    const int n = blockIdx.x;
    const int slab = n >> 7, rn = n & 127;
    const int srow = (rn >> 1) & 3;
    for (int k = threadIdx.x; k < NUMD; k += 256) {
        float v = W[(size_t)k * NUMD + n];
        if (k == n) v = 0.0f;
        Wt[(size_t)n * NUMD + k] = v;          // unscaled fp32 for inline fix
        const float vs = v * SW;
        f16 h  = (f16)vs;
        f16 lo = (f16)(vs - (float)h);         // unscaled residual
        const int kt = k >> 5, kk = k & 31, c = kk >> 3, e = kk & 7;
        const int p = c ^ srow;
        const size_t off = (size_t)slab * SLAB_F16 + (size_t)kt * TILE_F16
                         + rn * 32 + p * 8 + e;
        WtH[off] = h; WtL[off] = lo;
    }
}

// ---------------- main GEMM (fused A-split + inline fixup) ----------------
__global__ __launch_bounds__(256, 2) void li_mfma(
    const float* __restrict__ A,    // [M,512] fp32
    const f16* __restrict__ WtH, const f16* __restrict__ WtL, // tiled
    const float* __restrict__ Wt,   // [n][k] fp32 diag-zeroed (inline fix)
    const float* __restrict__ bias,
    float* __restrict__ out,
    int M, int cpx)
{
    // [2 bufs][4 planes: AH AL BH BL][128 rows][32 k] f16 = 64 KiB.
    // After the K-loop this aliases cbuf[128][128] fp32 (same 64 KiB).
    __shared__ __align__(16) f16 lds[2][4][128][32];
    __shared__ unsigned flist[FLCAP];
    __shared__ unsigned lcnt;

    const int tid = threadIdx.x;
    const int l   = tid & 63;
    const int wv  = tid >> 6;     // wave 0..3
    const int wr  = wv >> 1;      // wave row 0..1
    const int wc  = wv & 1;       // wave col 0..1
    const int lG  = l >> 4;       // k-chunk group 0..3
    const int lM  = l & 15;       // frag row/col

    int w = blockIdx.x;
    if (cpx) { const int xcd = w & 7, c = w >> 3; w = xcd * cpx + c; }
    const int m0  = (w >> 2) * 128;
    const int n0b = (w & 3) * 128;

    // ---- B DMA source (tiled planes, contiguous 1KB per instruction)
    const size_t bOff = ((size_t)(n0b >> 7) * SLAB_F16) * 2 + wv * 2048 + l * 16;
    const char* pBH = (const char*)WtH;
    const char* pBL = (const char*)WtL;

#define STAGE_B(nb, ktb) do {                                                  \
    GLOAD_LDS16(pBH + bOff + (ktb),        &lds[nb][2][wv * 32][0]);           \
    GLOAD_LDS16(pBH + bOff + (ktb) + 1024, &lds[nb][2][wv * 32 + 16][0]);      \
    GLOAD_LDS16(pBL + bOff + (ktb),        &lds[nb][3][wv * 32][0]);           \
    GLOAD_LDS16(pBL + bOff + (ktb) + 1024, &lds[nb][3][wv * 32 + 16][0]);      \
  } while (0)

    // ---- A staging (reg path): tasks {tid, tid+256}; row=i>>2, chunk c=i&3.
    const int r0 = tid >> 2, ca = tid & 3;
    const int r1 = r0 + 64;
    const float* aBase0 = A + (size_t)(m0 + r0) * NUMD + ca * 8;
    const float* aBase1 = A + (size_t)(m0 + r1) * NUMD + ca * 8;
    const int wo0 = r0 * 64 + ((ca ^ ((r0 >> 1) & 3)) << 4);
    const int wo1 = r1 * 64 + ((ca ^ ((r1 >> 1) & 3)) << 4);

    float4 av00, av01, av10, av11;

#define ALOAD(kt) do {                                                         \
    const float* s0 = aBase0 + (size_t)(kt) * 32;                              \
    const float* s1 = aBase1 + (size_t)(kt) * 32;                              \
    av00 = *(const float4*)s0; av01 = *(const float4*)(s0 + 4);                \
    av10 = *(const float4*)s1; av11 = *(const float4*)(s1 + 4);                \
  } while (0)

#define ACONV(nb) do {                                                         \
    const float a0[8] = {av00.x, av00.y, av00.z, av00.w,                       \
                         av01.x, av01.y, av01.z, av01.w};                      \
    const float a1[8] = {av10.x, av10.y, av10.z, av10.w,                       \
                         av11.x, av11.y, av11.z, av11.w};                      \
    f16x8 h0, lo0, h1, lo1;                                                    \
    _Pragma("unroll")                                                          \
    for (int e = 0; e < 8; ++e) {                                              \
        float as0 = a0[e] * SA; f16 hv0 = (f16)as0;                            \
        h0[e] = hv0; lo0[e] = (f16)(as0 - (float)hv0);                         \
        float as1 = a1[e] * SA; f16 hv1 = (f16)as1;                            \
        h1[e] = hv1; lo1[e] = (f16)(as1 - (float)hv1);                         \
    }                                                                          \
    *(f16x8*)((char*)&lds[nb][0][0][0] + wo0) = h0;                            \
    *(f16x8*)((char*)&lds[nb][1][0][0] + wo0) = lo0;                           \
    *(f16x8*)((char*)&lds[nb][0][0][0] + wo1) = h1;                            \
    *(f16x8*)((char*)&lds[nb][1][0][0] + wo1) = lo1;                           \
  } while (0)

    int aRd[4], bRd[4];
#pragma unroll
    for (int f = 0; f < 4; ++f) {
        const int mr = wr * 64 + f * 16 + lM;
        aRd[f] = mr * 64 + ((lG ^ ((mr >> 1) & 3)) << 4);
        const int nr = wc * 64 + f * 16 + lM;
        bRd[f] = nr * 64 + ((lG ^ ((nr >> 1) & 3)) << 4);
    }

    f32x4 acc[4][4];
#pragma unroll
    for (int i = 0; i < 4; ++i)
#pragma unroll
        for (int j = 0; j < 4; ++j) acc[i][j] = f32x4{0.f, 0.f, 0.f, 0.f};

    // prologue: tile 0
    ALOAD(0);
    STAGE_B(0, 0);
    ACONV(0);

    const int NT = NUMD / 32;   // 16
    for (int kt = 0; kt < NT; ++kt) {
        const int cur = kt & 1;
        __syncthreads();        // publishes tile kt (DMA vmcnt + ds_writes + barrier)

        if (kt + 1 < NT) {
            STAGE_B(cur ^ 1, (size_t)(kt + 1) * 8192);
            ALOAD(kt + 1);
        }

        const char* PAH = (const char*)&lds[cur][0][0][0];
        const char* PAL = (const char*)&lds[cur][1][0][0];
        const char* PBH = (const char*)&lds[cur][2][0][0];
        const char* PBL = (const char*)&lds[cur][3][0][0];

        f16x8 bh[4], bl[4];
#pragma unroll
        for (int fj = 0; fj < 4; ++fj) {
            bh[fj] = *(const f16x8*)(PBH + bRd[fj]);
            bl[fj] = *(const f16x8*)(PBL + bRd[fj]);
        }
        __builtin_amdgcn_s_setprio(1);
#pragma unroll
        for (int fi = 0; fi < 4; ++fi) {
            const f16x8 ah = *(const f16x8*)(PAH + aRd[fi]);
            const f16x8 al = *(const f16x8*)(PAL + aRd[fi]);
#pragma unroll
            for (int fj = 0; fj < 4; ++fj) {
                acc[fi][fj] = __builtin_amdgcn_mfma_f32_16x16x32_f16(ah, bh[fj], acc[fi][fj], 0, 0, 0);
                acc[fi][fj] = __builtin_amdgcn_mfma_f32_16x16x32_f16(ah, bl[fj], acc[fi][fj], 0, 0, 0);
                acc[fi][fj] = __builtin_amdgcn_mfma_f32_16x16x32_f16(al, bh[fj], acc[fi][fj], 0, 0, 0);
            }
        }
        __builtin_amdgcn_s_setprio(0);

        if (kt + 1 < NT) ACONV(cur ^ 1);
    }

    // ================= epilogue =================
    __syncthreads();                       // staging LDS dead
    float* cbuf = (float*)&lds[0][0][0][0];   // [128][128] fp32, 64 KiB
    if (tid == 0) lcnt = 0;

    // writer: scatter acc*2^-25 into cbuf (C/D layout col=lane&15,
    // row=(lane>>4)*4+reg -- m89-verified)
#pragma unroll
    for (int fj = 0; fj < 4; ++fj) {
        const int cl = wc * 64 + fj * 16 + lM;
#pragma unroll
        for (int fi = 0; fi < 4; ++fi) {
            const int rl = wr * 64 + fi * 16 + lG * 4;
#pragma unroll
            for (int r = 0; r < 4; ++r)
                cbuf[(rl + r) * 128 + cl] = acc[fi][fj][r] * INV_S;
        }
    }
    __syncthreads();

    // reader: coalesced float4 gate + store; flag near-zero to LDS list
    const int rcol = (tid & 31) * 4;
    const float4 bv4 = *(const float4*)(bias + n0b + rcol);
#pragma unroll
    for (int ch = 0; ch < 16; ++ch) {
        const int rrow = ch * 8 + (tid >> 5);
        const float4 v = *(const float4*)&cbuf[rrow * 128 + rcol];
        const size_t gi = (size_t)(m0 + rrow) * NUMD + n0b + rcol;
        const float4 x = *(const float4*)(A + gi);
        const float inh0 = v.x + bv4.x, inh1 = v.y + bv4.y;
        const float inh2 = v.z + bv4.z, inh3 = v.w + bv4.w;
        float4 o;
        o.x = (inh0 > 0.0f) ? x.x : 0.0f;
        o.y = (inh1 > 0.0f) ? x.y : 0.0f;
        o.z = (inh2 > 0.0f) ? x.z : 0.0f;
        o.w = (inh3 > 0.0f) ? x.w : 0.0f;
        *(float4*)(out + gi) = o;
        if (__builtin_fabsf(inh0) <= EPS) { unsigned p = atomicAdd(&lcnt, 1u); if (p < FLCAP) flist[p] = (unsigned)(gi + 0); }
        if (__builtin_fabsf(inh1) <= EPS) { unsigned p = atomicAdd(&lcnt, 1u); if (p < FLCAP) flist[p] = (unsigned)(gi + 1); }
        if (__builtin_fabsf(inh2) <= EPS) { unsigned p = atomicAdd(&lcnt, 1u); if (p < FLCAP) flist[p] = (unsigned)(gi + 2); }
        if (__builtin_fabsf(inh3) <= EPS) { unsigned p = atomicAdd(&lcnt, 1u); if (p < FLCAP) flist[p] = (unsigned)(gi + 3); }
    }

    // inline fix: exact fp32 recompute, BIT-IDENTICAL op order to the proven
    // v4 path (k-ascending fmaf chain). Barrier drained bulk stores (vmcnt 0).
    __syncthreads();
    unsigned nf = lcnt; if (nf > FLCAP) nf = FLCAP;
    for (unsigned e = tid; e < nf; e += 256) {
        const unsigned code = flist[e];
        const int n = (int)(code & 511);
        const float* ar  = A  + (size_t)(code >> 9) * NUMD;
        const float* wr_ = Wt + (size_t)n * NUMD;
        float s = 0.0f;
#pragma unroll 8
        for (int k = 0; k < NUMD; ++k)
            s = fmaf(ar[k], wr_[k], s);        // strict k-ascending chain
        const float inh = s + bias[n];
        out[code] = (inh > 0.0f) ? A[code] : 0.0f;
    }
#undef STAGE_B
#undef ALOAD
#undef ACONV
}

// ---------------- fallback: v4 exact fp32 path (proven 205us) ----------------
#define BM 128
#define BN 256
#define BK 16
#define TM 8
#define TN 16
#define NTF (NUMD / BK)

__global__ __launch_bounds__(256) void zero_diag_kernel(
    const float* __restrict__ W, float* __restrict__ Wz)
{
    const int f = (int)(blockIdx.x * blockDim.x + threadIdx.x) * 4;
    const int row = f >> 9, col0 = f & 511;
    float4 v = *(const float4*)(W + f);
    if (row == col0 + 0) v.x = 0.0f;
    if (row == col0 + 1) v.y = 0.0f;
    if (row == col0 + 2) v.z = 0.0f;
    if (row == col0 + 3) v.w = 0.0f;
    *(float4*)(Wz + f) = v;
}

template<bool ZDIAG>
__global__ __launch_bounds__(256, 1) void li_gemm_fp32(
    const float* __restrict__ A, const float* __restrict__ Wm,
    const float* __restrict__ bias, float* __restrict__ out, int M)
{
    __shared__ __align__(16) float As[2][BM][BK];
    __shared__ __align__(16) float Bs[2][BK][BN];
    const int tid = threadIdx.x, lane = tid & 63, wv = tid >> 6;
    const int tc = tid & 15, tr = tid >> 4;
    const int m0 = blockIdx.x * BM, n0 = blockIdx.y * BN;
    const int am0 = wv * 32 + (lane >> 2), am1 = am0 + 16;
    const int q0 = ((lane & 3) ^ ((am0 >> 3) & 3)) << 2;
    const int q1 = ((lane & 3) ^ ((am1 >> 3) & 3)) << 2;
    const float* aSrc0 = A + (size_t)(m0 + am0) * NUMD + q0;
    const float* aSrc1 = A + (size_t)(m0 + am1) * NUMD + q1;
    const float* wSrc = Wm + (size_t)(wv * 4) * NUMD + n0 + lane * 4;
    float acc[TM][TN];
#pragma unroll
    for (int i = 0; i < TM; ++i)
#pragma unroll
        for (int j = 0; j < TN; ++j) acc[i][j] = 0.0f;
    GLOAD_LDS16(aSrc0, &As[0][wv * 32][0]);
    GLOAD_LDS16(aSrc1, &As[0][wv * 32 + 16][0]);
#pragma unroll
    for (int r = 0; r < 4; ++r)
        GLOAD_LDS16(wSrc + (size_t)r * NUMD, &Bs[0][wv * 4 + r][0]);
    aSrc0 += BK; aSrc1 += BK; wSrc += (size_t)BK * NUMD;
    for (int kt = 0; kt < NTF; ++kt) {
        const int cur = kt & 1;
        __syncthreads();
        if (kt + 1 < NTF) {
            const int nb = cur ^ 1;
            GLOAD_LDS16(aSrc0, &As[nb][wv * 32][0]);
            GLOAD_LDS16(aSrc1, &As[nb][wv * 32 + 16][0]);
#pragma unroll
            for (int r = 0; r < 4; ++r)
                GLOAD_LDS16(wSrc + (size_t)r * NUMD, &Bs[nb][wv * 4 + r][0]);
            aSrc0 += BK; aSrc1 += BK; wSrc += (size_t)BK * NUMD;
        }
        if (ZDIAG) {
            const int kk = kt * BK;
            if (tid < BK) {
                const int col = kk + tid - n0;
                if (col >= 0 && col < BN) Bs[cur][tid][col] = 0.0f;
            }
            __syncthreads();
        }
#pragma unroll
        for (int g = 0; g < 4; ++g) {
            float4 af[TM];
#pragma unroll
            for (int i = 0; i < TM; ++i) {
                const int m = tr * TM + i;
                af[i] = *(const float4*)&As[cur][m][(g ^ ((m >> 3) & 3)) << 2];
            }
#pragma unroll
            for (int dk = 0; dk < 4; ++dk) {
                float b[TN];
#pragma unroll
                for (int c = 0; c < 4; ++c) {
                    float4 b4 = *(const float4*)&Bs[cur][g * 4 + dk][tc * 4 + 64 * c];
                    b[4*c+0] = b4.x; b[4*c+1] = b4.y; b[4*c+2] = b4.z; b[4*c+3] = b4.w;
                }
#pragma unroll
                for (int i = 0; i < TM; ++i) {
                    const float a = ((const float*)&af[i])[dk];
#pragma unroll
                    for (int j = 0; j < TN; ++j) acc[i][j] = fmaf(a, b[j], acc[i][j]);
                }
            }
        }
    }
    float bv[TN];
#pragma unroll
    for (int c = 0; c < 4; ++c) {
        float4 b4 = *(const float4*)(bias + n0 + tc * 4 + 64 * c);
        bv[4*c+0] = b4.x; bv[4*c+1] = b4.y; bv[4*c+2] = b4.z; bv[4*c+3] = b4.w;
    }
#pragma unroll
    for (int i = 0; i < TM; ++i) {
        const int gm = m0 + tr * TM + i;
        const float* inrow = A + (size_t)gm * NUMD + n0 + tc * 4;
        float* orow = out + (size_t)gm * NUMD + n0 + tc * 4;
#pragma unroll
        for (int c = 0; c < 4; ++c) {
            float4 x = *(const float4*)(inrow + 64 * c);
            float4 o;
            o.x = (acc[i][4*c+0] + bv[4*c+0] > 0.0f) ? x.x : 0.0f;
            o.y = (acc[i][4*c+1] + bv[4*c+1] > 0.0f) ? x.y : 0.0f;
            o.z = (acc[i][4*c+2] + bv[4*c+2] > 0.0f) ? x.z : 0.0f;
            o.w = (acc[i][4*c+3] + bv[4*c+3] > 0.0f) ? x.w : 0.0f;
            *(float4*)(orow + 64 * c) = o;
        }
    }
}

extern "C" void kernel_launch(void* const* d_in, const int* in_sizes, int n_in,
                              void* d_out, int out_size, void* d_ws, size_t ws_size,
                              hipStream_t stream) {
    const float* A    = (const float*)d_in[0];
    const float* W    = (const float*)d_in[1];
    const float* bias = (const float*)d_in[2];
    float* out        = (float*)d_out;
    const int M = in_sizes[0] / NUMD;           // 32768

    const size_t need = (2u << 20) + 4096;

    if (ws_size >= need) {
        char* wsb = (char*)d_ws;
        float* Wt  = (float*)wsb;                              // 1 MiB
        f16*   WtH = (f16*)(wsb + (1u << 20));                 // 512 KiB tiled
        f16*   WtL = (f16*)(wsb + (1u << 20) + (512u << 10));  // 512 KiB tiled

        prep<<<dim3(NUMD), 256, 0, stream>>>(W, Wt, WtH, WtL);
        const int nwg = (M / 128) * (NUMD / 128);
        const int cpx = (nwg % 8 == 0) ? (nwg / 8) : 0;
        li_mfma<<<dim3(nwg), 256, 0, stream>>>(A, WtH, WtL, Wt, bias, out,
                                               M, cpx);
    } else {
        dim3 grid(M / BM, NUMD / BN);
        const size_t wbytes = (size_t)NUMD * NUMD * sizeof(float);
        if (ws_size >= wbytes) {
            float* Wz = (float*)d_ws;
            zero_diag_kernel<<<dim3(NUMD * NUMD / (4 * 256)), 256, 0, stream>>>(W, Wz);
            li_gemm_fp32<false><<<grid, 256, 0, stream>>>(A, Wz, bias, out, M);
        } else {
            li_gemm_fp32<true><<<grid, 256, 0, stream>>>(A, W, bias, out, M);
        }
    }
}